// Round 1
// baseline (6932.139 us; speedup 1.0000x reference)
//
#include <hip/hip_runtime.h>
#include <math.h>

#define BSZ 4
#define Lseq 2048
#define DM 64
#define ED 128
#define NST 32
#define DCONVK 16
#define NLAYERS 4
#define DTRANK 4
#define EPSV 1e-5f

__device__ __forceinline__ float sigf(float x) { return 1.0f / (1.0f + __expf(-x)); }

// ---------------- K1: rmsnorm + input projection (64 -> 256), split into xin/z
__global__ __launch_bounds__(256) void k_rms_inproj(
    const float* __restrict__ h, const float* __restrict__ in_w,
    const float* __restrict__ in_b, const float* __restrict__ norm_w,
    float* __restrict__ xin, float* __restrict__ zb)
{
    const int token = blockIdx.x;      // b*L + l
    const int t = threadIdx.x;         // 0..255 = output channel e
    __shared__ float hn[DM];
    __shared__ float sc;
    const float* hrow = h + (size_t)token * DM;
    float v = 0.f;
    if (t < DM) {
        v = hrow[t];
        float ss = v * v;
        #pragma unroll
        for (int off = 32; off; off >>= 1) ss += __shfl_xor(ss, off, 64);
        if (t == 0) sc = rsqrtf(ss * (1.0f / DM) + EPSV);
    }
    __syncthreads();
    if (t < DM) hn[t] = v * sc * norm_w[t];
    __syncthreads();
    float acc = in_b[t];
    const float* wrow = in_w + t * DM;
    #pragma unroll
    for (int d = 0; d < DM; ++d) acc = fmaf(hn[d], wrow[d], acc);
    if (t < ED) xin[(size_t)token * ED + t] = acc;
    else        zb[(size_t)token * ED + (t - ED)] = acc;
}

// ---------------- K2: causal dwconv + silu -> xc ; xproj -> (dt_raw, B, C) ; dtproj+softplus -> delta
__global__ __launch_bounds__(128) void k_conv_proj(
    const float* __restrict__ xin, const float* __restrict__ conv_w,
    const float* __restrict__ conv_b, const float* __restrict__ xproj_w,
    const float* __restrict__ dtproj_w, const float* __restrict__ dtproj_b,
    float* __restrict__ xc_out, float* __restrict__ delta_out,
    float* __restrict__ Bout, float* __restrict__ Cout)
{
    const int token = blockIdx.x;           // b*L + l
    const int l = token & (Lseq - 1);
    const int t = threadIdx.x;              // e (0..127)
    __shared__ float xcs[ED];
    __shared__ float dts[DTRANK];

    float acc = conv_b[t];
    const float* w = conv_w + t * DCONVK;
    const int kmin = (l >= DCONVK - 1) ? 0 : (DCONVK - 1 - l);
    const float* xptr = xin + ((long long)token - (DCONVK - 1)) * ED + t;
    for (int k = kmin; k < DCONVK; ++k) acc = fmaf(xptr[(long long)k * ED], w[k], acc);
    float xc = acc * sigf(acc);             // silu
    xcs[t] = xc;
    xc_out[(size_t)token * ED + t] = xc;
    __syncthreads();

    if (t < DTRANK + 2 * NST) {
        float a = 0.f;
        const float* pw = xproj_w + t * ED;
        #pragma unroll 8
        for (int e = 0; e < ED; ++e) a = fmaf(xcs[e], pw[e], a);
        if (t < DTRANK)            dts[t] = a;
        else if (t < DTRANK + NST) Bout[(size_t)token * NST + (t - DTRANK)] = a;
        else                       Cout[(size_t)token * NST + (t - DTRANK - NST)] = a;
    }
    __syncthreads();

    {
        const float* dw = dtproj_w + t * DTRANK;
        float a = dtproj_b[t];
        #pragma unroll
        for (int r = 0; r < DTRANK; ++r) a = fmaf(dts[r], dw[r], a);
        float sp = fmaxf(a, 0.f) + log1pf(__expf(-fabsf(a)));   // stable softplus
        delta_out[(size_t)token * ED + t] = sp;
    }
}

// ---------------- K3: selective scan. 1 wave = 2 e-channels x 32 states.
// last==0: write y[b,l,e] for all l.  last==1: write y only at l=L-1 into yout[b*ED+e].
__global__ __launch_bounds__(64) void k_scan(
    const float* __restrict__ delta, const float* __restrict__ Bv,
    const float* __restrict__ Cv, const float* __restrict__ xc,
    const float* __restrict__ zb, const float* __restrict__ A_log,
    const float* __restrict__ Dp, float* __restrict__ yout, int last)
{
    const int b = blockIdx.y;
    const int e = blockIdx.x * 2 + (threadIdx.x >> 5);
    const int n = threadIdx.x & 31;
    const float Aen = -__expf(A_log[e * NST + n]);
    const float dpe = Dp[e];
    float hs = 0.f;
    const size_t base = (size_t)b * Lseq;
    for (int l = 0; l < Lseq; ++l) {
        const size_t tok = base + l;
        const float de  = delta[tok * ED + e];
        const float Bn  = Bv[tok * NST + n];
        const float Cn  = Cv[tok * NST + n];
        const float xce = xc[tok * ED + e];
        const float a = __expf(de * Aen);
        hs = fmaf(a, hs, de * Bn * xce);
        if (!last || l == Lseq - 1) {
            float p = hs * Cn;
            #pragma unroll
            for (int off = 16; off; off >>= 1) p += __shfl_xor(p, off, 32);
            if (n == 0) {
                const float zi = zb[tok * ED + e];
                const float yv = (p + dpe * xce) * (zi * sigf(zi));
                if (!last) yout[tok * ED + e] = yv;
                else       yout[(size_t)b * ED + e] = yv;
            }
        }
    }
}

// ---------------- K4: out projection (128 -> 64) + residual add
__global__ __launch_bounds__(64) void k_outproj(
    const float* __restrict__ y, const float* __restrict__ ow,
    const float* __restrict__ ob, const float* __restrict__ hin,
    float* __restrict__ hout)
{
    const int token = blockIdx.x;
    const int d = threadIdx.x;       // 0..63
    __shared__ float ys[ED];
    ys[d]      = y[(size_t)token * ED + d];
    ys[d + 64] = y[(size_t)token * ED + d + 64];
    __syncthreads();
    float acc = ob[d];
    const float* w = ow + d * ED;
    #pragma unroll 8
    for (int e = 0; e < ED; ++e) acc = fmaf(ys[e], w[e], acc);
    hout[(size_t)token * DM + d] = hin[(size_t)token * DM + d] + acc;
}

// ---------------- K5: classifier head on y[:, L-1, :]
__global__ __launch_bounds__(64) void k_final(
    const float* __restrict__ ylast, const float* __restrict__ fcw,
    const float* __restrict__ fcb, float* __restrict__ out)
{
    const int b = blockIdx.x;
    const int t = threadIdx.x;
    float a = ylast[(size_t)b * ED + t] * fcw[t]
            + ylast[(size_t)b * ED + 64 + t] * fcw[64 + t];
    #pragma unroll
    for (int off = 32; off; off >>= 1) a += __shfl_xor(a, off, 64);
    if (t == 0) out[b] = a + fcb[0];
}

extern "C" void kernel_launch(void* const* d_in, const int* in_sizes, int n_in,
                              void* d_out, int out_size, void* d_ws, size_t ws_size,
                              hipStream_t stream)
{
    const float* x         = (const float*)d_in[0];
    const float* in_w      = (const float*)d_in[1];
    const float* in_b      = (const float*)d_in[2];
    const float* conv_w    = (const float*)d_in[3];
    const float* conv_b    = (const float*)d_in[4];
    const float* xproj_w   = (const float*)d_in[5];
    const float* dtproj_w  = (const float*)d_in[6];
    const float* dtproj_b  = (const float*)d_in[7];
    const float* A_log     = (const float*)d_in[8];
    const float* Dp        = (const float*)d_in[9];
    const float* outproj_w = (const float*)d_in[10];
    const float* outproj_b = (const float*)d_in[11];
    const float* norm_w    = (const float*)d_in[12];
    const float* fc_w      = (const float*)d_in[13];
    const float* fc_b      = (const float*)d_in[14];

    const size_t TOK = (size_t)BSZ * Lseq;
    float* ws = (float*)d_ws;
    float* h0   = ws; ws += TOK * DM;
    float* h1   = ws; ws += TOK * DM;
    float* xin  = ws; ws += TOK * ED;   // after k_conv_proj, reused as y
    float* zbuf = ws; ws += TOK * ED;
    float* xc   = ws; ws += TOK * ED;
    float* dlt  = ws; ws += TOK * ED;
    float* Bv   = ws; ws += TOK * NST;
    float* Cv   = ws; ws += TOK * NST;

    const float* hin = x;
    float* hbufs[2] = { h0, h1 };

    for (int i = 0; i < NLAYERS; ++i) {
        const int last = (i == NLAYERS - 1);
        k_rms_inproj<<<(int)TOK, 256, 0, stream>>>(
            hin, in_w + (size_t)i * 2 * ED * DM, in_b + (size_t)i * 2 * ED,
            norm_w + (size_t)i * DM, xin, zbuf);
        k_conv_proj<<<(int)TOK, 128, 0, stream>>>(
            xin, conv_w + (size_t)i * ED * DCONVK, conv_b + (size_t)i * ED,
            xproj_w + (size_t)i * (DTRANK + 2 * NST) * ED,
            dtproj_w + (size_t)i * ED * DTRANK, dtproj_b + (size_t)i * ED,
            xc, dlt, Bv, Cv);
        // y aliases xin (xin is dead after k_conv_proj)
        k_scan<<<dim3(ED / 2, BSZ), 64, 0, stream>>>(
            dlt, Bv, Cv, xc, zbuf,
            A_log + (size_t)i * ED * NST, Dp + (size_t)i * ED, xin, last);
        if (!last) {
            float* hout = hbufs[i & 1];
            k_outproj<<<(int)TOK, 64, 0, stream>>>(
                xin, outproj_w + (size_t)i * DM * ED, outproj_b + (size_t)i * DM,
                hin, hout);
            hin = hout;
        }
    }
    k_final<<<BSZ, 64, 0, stream>>>(xin, fc_w, fc_b, (float*)d_out);
}

// Round 2
// 959.811 us; speedup vs baseline: 7.2224x; 7.2224x over previous
//
#include <hip/hip_runtime.h>
#include <math.h>

#define BSZ 4
#define Lseq 2048
#define DM 64
#define ED 128
#define NST 32
#define DCONVK 16
#define NLAYERS 4
#define DTRANK 4
#define EPSV 1e-5f
#define NC 32                 // chunks along L
#define LC (Lseq / NC)        // 64 steps per chunk

__device__ __forceinline__ float sigf(float x) { return 1.0f / (1.0f + __expf(-x)); }

// ---------------- K1: rmsnorm + input projection (64 -> 256), split into xin/z
__global__ __launch_bounds__(256) void k_rms_inproj(
    const float* __restrict__ h, const float* __restrict__ in_w,
    const float* __restrict__ in_b, const float* __restrict__ norm_w,
    float* __restrict__ xin, float* __restrict__ zb)
{
    const int token = blockIdx.x;      // b*L + l
    const int t = threadIdx.x;         // 0..255 = output channel e
    __shared__ float hn[DM];
    __shared__ float sc;
    const float* hrow = h + (size_t)token * DM;
    float v = 0.f;
    if (t < DM) {
        v = hrow[t];
        float ss = v * v;
        #pragma unroll
        for (int off = 32; off; off >>= 1) ss += __shfl_xor(ss, off, 64);
        if (t == 0) sc = rsqrtf(ss * (1.0f / DM) + EPSV);
    }
    __syncthreads();
    if (t < DM) hn[t] = v * sc * norm_w[t];
    __syncthreads();
    float acc = in_b[t];
    const float* wrow = in_w + t * DM;
    #pragma unroll
    for (int d = 0; d < DM; ++d) acc = fmaf(hn[d], wrow[d], acc);
    if (t < ED) xin[(size_t)token * ED + t] = acc;
    else        zb[(size_t)token * ED + (t - ED)] = acc;
}

// ---------------- K2: causal dwconv + silu -> xc ; xproj -> (dt,B,C) ; dtproj+softplus -> delta
__global__ __launch_bounds__(128) void k_conv_proj(
    const float* __restrict__ xin, const float* __restrict__ conv_w,
    const float* __restrict__ conv_b, const float* __restrict__ xproj_w,
    const float* __restrict__ dtproj_w, const float* __restrict__ dtproj_b,
    float* __restrict__ xc_out, float* __restrict__ delta_out,
    float* __restrict__ Bout, float* __restrict__ Cout)
{
    const int token = blockIdx.x;           // b*L + l
    const int l = token & (Lseq - 1);
    const int t = threadIdx.x;              // e (0..127)
    __shared__ float xcs[ED];
    __shared__ float dts[DTRANK];

    float acc = conv_b[t];
    const float* w = conv_w + t * DCONVK;
    const int kmin = (l >= DCONVK - 1) ? 0 : (DCONVK - 1 - l);
    const float* xptr = xin + ((long long)token - (DCONVK - 1)) * ED + t;
    for (int k = kmin; k < DCONVK; ++k) acc = fmaf(xptr[(long long)k * ED], w[k], acc);
    float xc = acc * sigf(acc);             // silu
    xcs[t] = xc;
    xc_out[(size_t)token * ED + t] = xc;
    __syncthreads();

    if (t < DTRANK + 2 * NST) {
        float a = 0.f;
        const float* pw = xproj_w + t * ED;
        #pragma unroll 8
        for (int e = 0; e < ED; ++e) a = fmaf(xcs[e], pw[e], a);
        if (t < DTRANK)            dts[t] = a;
        else if (t < DTRANK + NST) Bout[(size_t)token * NST + (t - DTRANK)] = a;
        else                       Cout[(size_t)token * NST + (t - DTRANK - NST)] = a;
    }
    __syncthreads();

    {
        const float* dw = dtproj_w + t * DTRANK;
        float a = dtproj_b[t];
        #pragma unroll
        for (int r = 0; r < DTRANK; ++r) a = fmaf(dts[r], dw[r], a);
        float sp = fmaxf(a, 0.f) + log1pf(__expf(-fabsf(a)));   // stable softplus
        delta_out[(size_t)token * ED + t] = sp;
    }
}

// ---------------- K3a: per-chunk local scan (from zero state). block=128: 4 e-ch x 32 n.
__global__ __launch_bounds__(128) void k_scan_local(
    const float* __restrict__ delta, const float* __restrict__ Bv,
    const float* __restrict__ xc, const float* __restrict__ A_log,
    float* __restrict__ aprod, float* __restrict__ hloc)
{
    const int b = blockIdx.z;
    const int c = blockIdx.x;
    const int e = blockIdx.y * 4 + (threadIdx.x >> 5);
    const int n = threadIdx.x & 31;
    const float Aen = -__expf(A_log[e * NST + n]);
    float hs = 0.f, ap = 1.f;
    const size_t base = (size_t)b * Lseq + (size_t)c * LC;
    #pragma unroll 4
    for (int l = 0; l < LC; ++l) {
        const size_t tok = base + l;
        const float de  = delta[tok * ED + e];
        const float Bn  = Bv[tok * NST + n];
        const float xce = xc[tok * ED + e];
        const float a = __expf(de * Aen);
        hs = fmaf(a, hs, de * Bn * xce);
        ap *= a;
    }
    const size_t idx = (((size_t)b * NC + c) * ED + e) * NST + n;
    aprod[idx] = ap;
    hloc[idx]  = hs;
}

// ---------------- K3b: chunk-level combine. hloc is rewritten in place to the chunk
// INITIAL states; final state goes to hend[b,e,n]. One thread per (b,e,n).
__global__ __launch_bounds__(256) void k_scan_combine(
    const float* __restrict__ aprod, float* __restrict__ hloc,
    float* __restrict__ hend)
{
    const int tid = blockIdx.x * 256 + threadIdx.x;   // 0..16383
    const int b = tid >> 12;                          // ED*NST = 4096
    const int en = tid & 4095;
    size_t idx = (size_t)b * NC * (ED * NST) + en;
    float h = 0.f;
    #pragma unroll 4
    for (int c = 0; c < NC; ++c) {
        const float a = aprod[idx];
        const float u = hloc[idx];
        hloc[idx] = h;                // initial state for chunk c
        h = fmaf(a, h, u);
        idx += ED * NST;
    }
    hend[(size_t)b * (ED * NST) + en] = h;
}

// ---------------- K3c: per-chunk scan with correct initial state, emit y (non-last layers).
__global__ __launch_bounds__(128) void k_scan_y(
    const float* __restrict__ delta, const float* __restrict__ Bv,
    const float* __restrict__ Cv, const float* __restrict__ xc,
    const float* __restrict__ zb, const float* __restrict__ A_log,
    const float* __restrict__ Dp, const float* __restrict__ hinit,
    float* __restrict__ y)
{
    const int b = blockIdx.z;
    const int c = blockIdx.x;
    const int e = blockIdx.y * 4 + (threadIdx.x >> 5);
    const int n = threadIdx.x & 31;
    const float Aen = -__expf(A_log[e * NST + n]);
    const float dpe = Dp[e];
    float hs = hinit[(((size_t)b * NC + c) * ED + e) * NST + n];
    const size_t base = (size_t)b * Lseq + (size_t)c * LC;
    for (int l = 0; l < LC; ++l) {
        const size_t tok = base + l;
        const float de  = delta[tok * ED + e];
        const float Bn  = Bv[tok * NST + n];
        const float Cn  = Cv[tok * NST + n];
        const float xce = xc[tok * ED + e];
        const float a = __expf(de * Aen);
        hs = fmaf(a, hs, de * Bn * xce);
        float p = hs * Cn;
        #pragma unroll
        for (int off = 16; off; off >>= 1) p += __shfl_xor(p, off, 32);
        if (n == 0) {
            const float zi = zb[tok * ED + e];
            y[tok * ED + e] = (p + dpe * xce) * (zi * sigf(zi));
        }
    }
}

// ---------------- K4: out projection (128 -> 64) + residual add
__global__ __launch_bounds__(64) void k_outproj(
    const float* __restrict__ y, const float* __restrict__ ow,
    const float* __restrict__ ob, const float* __restrict__ hin,
    float* __restrict__ hout)
{
    const int token = blockIdx.x;
    const int d = threadIdx.x;       // 0..63
    __shared__ float ys[ED];
    ys[d]      = y[(size_t)token * ED + d];
    ys[d + 64] = y[(size_t)token * ED + d + 64];
    __syncthreads();
    float acc = ob[d];
    const float* w = ow + d * ED;
    #pragma unroll 8
    for (int e = 0; e < ED; ++e) acc = fmaf(ys[e], w[e], acc);
    hout[(size_t)token * DM + d] = hin[(size_t)token * DM + d] + acc;
}

// ---------------- K5: last layer head: y(L-1) from Hend, then fc dot -> logits
__global__ __launch_bounds__(128) void k_final_last(
    const float* __restrict__ hend, const float* __restrict__ Cv,
    const float* __restrict__ xc, const float* __restrict__ zb,
    const float* __restrict__ Dp, const float* __restrict__ fcw,
    const float* __restrict__ fcb, float* __restrict__ out)
{
    const int b = blockIdx.x;
    const int e = threadIdx.x;       // 0..127
    const size_t tok = (size_t)b * Lseq + (Lseq - 1);
    const float* hp = hend + (size_t)b * (ED * NST) + e * NST;
    const float* cp = Cv + tok * NST;
    float p = 0.f;
    #pragma unroll
    for (int n = 0; n < NST; ++n) p = fmaf(hp[n], cp[n], p);
    const float xce = xc[tok * ED + e];
    const float zi  = zb[tok * ED + e];
    float val = (p + Dp[e] * xce) * (zi * sigf(zi)) * fcw[e];
    __shared__ float sred[2];
    #pragma unroll
    for (int off = 32; off; off >>= 1) val += __shfl_xor(val, off, 64);
    if ((threadIdx.x & 63) == 0) sred[threadIdx.x >> 6] = val;
    __syncthreads();
    if (threadIdx.x == 0) out[b] = sred[0] + sred[1] + fcb[0];
}

extern "C" void kernel_launch(void* const* d_in, const int* in_sizes, int n_in,
                              void* d_out, int out_size, void* d_ws, size_t ws_size,
                              hipStream_t stream)
{
    const float* x         = (const float*)d_in[0];
    const float* in_w      = (const float*)d_in[1];
    const float* in_b      = (const float*)d_in[2];
    const float* conv_w    = (const float*)d_in[3];
    const float* conv_b    = (const float*)d_in[4];
    const float* xproj_w   = (const float*)d_in[5];
    const float* dtproj_w  = (const float*)d_in[6];
    const float* dtproj_b  = (const float*)d_in[7];
    const float* A_log     = (const float*)d_in[8];
    const float* Dp        = (const float*)d_in[9];
    const float* outproj_w = (const float*)d_in[10];
    const float* outproj_b = (const float*)d_in[11];
    const float* norm_w    = (const float*)d_in[12];
    const float* fc_w      = (const float*)d_in[13];
    const float* fc_b      = (const float*)d_in[14];

    const size_t TOK = (size_t)BSZ * Lseq;
    float* ws = (float*)d_ws;
    float* h0    = ws; ws += TOK * DM;
    float* h1    = ws; ws += TOK * DM;
    float* xin   = ws; ws += TOK * ED;   // after k_conv_proj, reused as y
    float* zbuf  = ws; ws += TOK * ED;
    float* xc    = ws; ws += TOK * ED;
    float* dlt   = ws; ws += TOK * ED;
    float* Bv    = ws; ws += TOK * NST;
    float* Cv    = ws; ws += TOK * NST;
    float* aprod = ws; ws += (size_t)BSZ * NC * ED * NST;
    float* hloc  = ws; ws += (size_t)BSZ * NC * ED * NST;   // becomes hinit in-place
    float* hend  = ws; ws += (size_t)BSZ * ED * NST;

    const float* hin = x;
    float* hbufs[2] = { h0, h1 };

    for (int i = 0; i < NLAYERS; ++i) {
        const int last = (i == NLAYERS - 1);
        k_rms_inproj<<<(int)TOK, 256, 0, stream>>>(
            hin, in_w + (size_t)i * 2 * ED * DM, in_b + (size_t)i * 2 * ED,
            norm_w + (size_t)i * DM, xin, zbuf);
        k_conv_proj<<<(int)TOK, 128, 0, stream>>>(
            xin, conv_w + (size_t)i * ED * DCONVK, conv_b + (size_t)i * ED,
            xproj_w + (size_t)i * (DTRANK + 2 * NST) * ED,
            dtproj_w + (size_t)i * ED * DTRANK, dtproj_b + (size_t)i * ED,
            xc, dlt, Bv, Cv);
        const float* Alog_i = A_log + (size_t)i * ED * NST;
        k_scan_local<<<dim3(NC, ED / 4, BSZ), 128, 0, stream>>>(
            dlt, Bv, xc, Alog_i, aprod, hloc);
        k_scan_combine<<<(BSZ * ED * NST) / 256, 256, 0, stream>>>(
            aprod, hloc, hend);
        if (!last) {
            k_scan_y<<<dim3(NC, ED / 4, BSZ), 128, 0, stream>>>(
                dlt, Bv, Cv, xc, zbuf, Alog_i, Dp + (size_t)i * ED, hloc, xin);
            float* hout = hbufs[i & 1];
            k_outproj<<<(int)TOK, 64, 0, stream>>>(
                xin, outproj_w + (size_t)i * DM * ED, outproj_b + (size_t)i * DM,
                hin, hout);
            hin = hout;
        } else {
            k_final_last<<<BSZ, 128, 0, stream>>>(
                hend, Cv, xc, zbuf, Dp + (size_t)i * ED, fc_w, fc_b, (float*)d_out);
        }
    }
}

// Round 3
// 859.678 us; speedup vs baseline: 8.0636x; 1.1165x over previous
//
#include <hip/hip_runtime.h>
#include <math.h>

#define BSZ 4
#define Lseq 2048
#define DM 64
#define ED 128
#define NST 32
#define DCONVK 16
#define NLAYERS 4
#define DTRANK 4
#define EPSV 1e-5f
#define NC 32                 // chunks along L
#define LC (Lseq / NC)        // 64 steps per chunk

__device__ __forceinline__ float sigf(float x) { return 1.0f / (1.0f + __expf(-x)); }

// ---------------- K1 (layer 0 only): rmsnorm + input projection (64 -> 256)
__global__ __launch_bounds__(256) void k_rms_inproj(
    const float* __restrict__ h, const float* __restrict__ in_w,
    const float* __restrict__ in_b, const float* __restrict__ norm_w,
    float* __restrict__ xin, float* __restrict__ zb)
{
    const int token = blockIdx.x;
    const int t = threadIdx.x;
    __shared__ __align__(16) float hn[DM];
    __shared__ float sc;
    const float* hrow = h + (size_t)token * DM;
    float v = 0.f;
    if (t < DM) {
        v = hrow[t];
        float ss = v * v;
        #pragma unroll
        for (int off = 32; off; off >>= 1) ss += __shfl_xor(ss, off, 64);
        if (t == 0) sc = rsqrtf(ss * (1.0f / DM) + EPSV);
    }
    __syncthreads();
    if (t < DM) hn[t] = v * sc * norm_w[t];
    __syncthreads();
    float acc = in_b[t];
    const float4* wr = (const float4*)(in_w + t * DM);
    const float4* h4 = (const float4*)hn;
    float a0 = 0.f, a1 = 0.f, a2 = 0.f, a3 = 0.f;
    #pragma unroll 8
    for (int i = 0; i < DM / 4; ++i) {
        float4 wv = wr[i], hv = h4[i];
        a0 = fmaf(hv.x, wv.x, a0); a1 = fmaf(hv.y, wv.y, a1);
        a2 = fmaf(hv.z, wv.z, a2); a3 = fmaf(hv.w, wv.w, a3);
    }
    acc += (a0 + a1) + (a2 + a3);
    if (t < ED) xin[(size_t)token * ED + t] = acc;
    else        zb[(size_t)token * ED + (t - ED)] = acc;
}

// ---------------- K-fused (layers 1..3): outproj(prev) + residual + rmsnorm + inproj
// Reads y (which aliases the xin buffer) then overwrites xin — safe: all y reads
// happen before the first __syncthreads, all xin writes after.
__global__ __launch_bounds__(256) void k_fused_layer(
    const float* __restrict__ y, const float* __restrict__ ow,
    const float* __restrict__ ob, const float* __restrict__ hin,
    const float* __restrict__ norm_w, const float* __restrict__ in_w,
    const float* __restrict__ in_b, float* __restrict__ hout,
    float* __restrict__ xin, float* __restrict__ zb)
{
    const int token = blockIdx.x;
    const int t = threadIdx.x;
    __shared__ __align__(16) float ys[ED];
    __shared__ __align__(16) float hn[DM];
    __shared__ float sc;

    if (t < ED / 4) ((float4*)ys)[t] = ((const float4*)(y + (size_t)token * ED))[t];
    __syncthreads();

    // outproj: output d = t>>2, quarter q = t&3 covers e in [q*32, q*32+32)
    {
        const int d = t >> 2, q = t & 3;
        const float4* wr = (const float4*)(ow + d * ED + q * 32);
        const float4* yv = (const float4*)(ys + q * 32);
        float a0 = 0.f, a1 = 0.f, a2 = 0.f, a3 = 0.f;
        #pragma unroll
        for (int i = 0; i < 8; ++i) {
            float4 wv = wr[i], hv = yv[i];
            a0 = fmaf(hv.x, wv.x, a0); a1 = fmaf(hv.y, wv.y, a1);
            a2 = fmaf(hv.z, wv.z, a2); a3 = fmaf(hv.w, wv.w, a3);
        }
        float p = (a0 + a1) + (a2 + a3);
        p += __shfl_xor(p, 1, 4);
        p += __shfl_xor(p, 2, 4);
        if (q == 0) {
            float hv = hin[(size_t)token * DM + d] + ob[d] + p;
            hout[(size_t)token * DM + d] = hv;
            hn[d] = hv;
        }
    }
    __syncthreads();
    if (t < DM) {
        float v = hn[t];
        float ss = v * v;
        #pragma unroll
        for (int off = 32; off; off >>= 1) ss += __shfl_xor(ss, off, 64);
        if (t == 0) sc = rsqrtf(ss * (1.0f / DM) + EPSV);
    }
    __syncthreads();
    if (t < DM) hn[t] = hn[t] * sc * norm_w[t];
    __syncthreads();
    {
        float acc = in_b[t];
        const float4* wr = (const float4*)(in_w + t * DM);
        const float4* h4 = (const float4*)hn;
        float a0 = 0.f, a1 = 0.f, a2 = 0.f, a3 = 0.f;
        #pragma unroll 8
        for (int i = 0; i < DM / 4; ++i) {
            float4 wv = wr[i], hv = h4[i];
            a0 = fmaf(hv.x, wv.x, a0); a1 = fmaf(hv.y, wv.y, a1);
            a2 = fmaf(hv.z, wv.z, a2); a3 = fmaf(hv.w, wv.w, a3);
        }
        acc += (a0 + a1) + (a2 + a3);
        if (t < ED) xin[(size_t)token * ED + t] = acc;
        else        zb[(size_t)token * ED + (t - ED)] = acc;
    }
}

// ---------------- K2: 2 tokens/block. causal dwconv + silu ; xproj ; dtproj+softplus
__global__ __launch_bounds__(256) void k_conv_proj(
    const float* __restrict__ xin, const float* __restrict__ conv_w,
    const float* __restrict__ conv_b, const float* __restrict__ xproj_w,
    const float* __restrict__ dtproj_w, const float* __restrict__ dtproj_b,
    float* __restrict__ xc_out, float* __restrict__ delta_out,
    float* __restrict__ Bout, float* __restrict__ Cout)
{
    const int ts = threadIdx.x >> 7;                 // token sub-index 0/1
    const int e  = threadIdx.x & 127;
    const int token = blockIdx.x * 2 + ts;
    const int l = token & (Lseq - 1);
    __shared__ __align__(16) float xcs[2][ED];
    __shared__ float dts[2][DTRANK];

    float acc = conv_b[e];
    const float* w = conv_w + e * DCONVK;
    const float* xptr = xin + ((long long)token - (DCONVK - 1)) * ED + e;
    if (l >= DCONVK - 1) {
        #pragma unroll
        for (int k = 0; k < DCONVK; ++k) acc = fmaf(xptr[(long long)k * ED], w[k], acc);
    } else {
        const int kmin = DCONVK - 1 - l;
        for (int k = kmin; k < DCONVK; ++k) acc = fmaf(xptr[(long long)k * ED], w[k], acc);
    }
    float xc = acc * sigf(acc);                      // silu
    xcs[ts][e] = xc;
    xc_out[(size_t)token * ED + e] = xc;
    __syncthreads();

    if (e < DTRANK + 2 * NST) {
        const float4* pw = (const float4*)(xproj_w + e * ED);
        const float4* xv = (const float4*)xcs[ts];
        float a0 = 0.f, a1 = 0.f, a2 = 0.f, a3 = 0.f;
        #pragma unroll 8
        for (int i = 0; i < ED / 4; ++i) {
            float4 wv = pw[i], hv = xv[i];
            a0 = fmaf(hv.x, wv.x, a0); a1 = fmaf(hv.y, wv.y, a1);
            a2 = fmaf(hv.z, wv.z, a2); a3 = fmaf(hv.w, wv.w, a3);
        }
        float a = (a0 + a1) + (a2 + a3);
        if (e < DTRANK)            dts[ts][e] = a;
        else if (e < DTRANK + NST) Bout[(size_t)token * NST + (e - DTRANK)] = a;
        else                       Cout[(size_t)token * NST + (e - DTRANK - NST)] = a;
    }
    __syncthreads();

    {
        const float* dw = dtproj_w + e * DTRANK;
        float a = dtproj_b[e];
        #pragma unroll
        for (int r = 0; r < DTRANK; ++r) a = fmaf(dts[ts][r], dw[r], a);
        float sp = fmaxf(a, 0.f) + log1pf(__expf(-fabsf(a)));   // stable softplus
        delta_out[(size_t)token * ED + e] = sp;
    }
}

// ---------------- K3a: per-chunk local scan (from zero state). block=128: 4 e-ch x 32 n.
__global__ __launch_bounds__(128) void k_scan_local(
    const float* __restrict__ delta, const float* __restrict__ Bv,
    const float* __restrict__ xc, const float* __restrict__ A_log,
    float* __restrict__ aprod, float* __restrict__ hloc)
{
    const int b = blockIdx.z;
    const int c = blockIdx.x;
    const int e = blockIdx.y * 4 + (threadIdx.x >> 5);
    const int n = threadIdx.x & 31;
    const float Aen = -__expf(A_log[e * NST + n]);
    float hs = 0.f, ap = 1.f;
    const size_t base = (size_t)b * Lseq + (size_t)c * LC;
    #pragma unroll 4
    for (int l = 0; l < LC; ++l) {
        const size_t tok = base + l;
        const float de  = delta[tok * ED + e];
        const float Bn  = Bv[tok * NST + n];
        const float xce = xc[tok * ED + e];
        const float a = __expf(de * Aen);
        hs = fmaf(a, hs, de * Bn * xce);
        ap *= a;
    }
    const size_t idx = (((size_t)b * NC + c) * ED + e) * NST + n;
    aprod[idx] = ap;
    hloc[idx]  = hs;
}

// ---------------- K3b (last layer only): chunk combine -> hend
__global__ __launch_bounds__(256) void k_scan_combine(
    const float* __restrict__ aprod, const float* __restrict__ hloc,
    float* __restrict__ hend)
{
    const int tid = blockIdx.x * 256 + threadIdx.x;   // 0..16383
    const int b = tid >> 12;                          // ED*NST = 4096
    const int en = tid & 4095;
    size_t idx = (size_t)b * NC * (ED * NST) + en;
    float h = 0.f;
    #pragma unroll 4
    for (int c = 0; c < NC; ++c) {
        h = fmaf(aprod[idx], h, hloc[idx]);
        idx += ED * NST;
    }
    hend[(size_t)b * (ED * NST) + en] = h;
}

// ---------------- K3c: per-chunk scan with inline chunk-prefix, emit y (non-last layers)
__global__ __launch_bounds__(128) void k_scan_y(
    const float* __restrict__ delta, const float* __restrict__ Bv,
    const float* __restrict__ Cv, const float* __restrict__ xc,
    const float* __restrict__ zb, const float* __restrict__ A_log,
    const float* __restrict__ Dp, const float* __restrict__ aprod,
    const float* __restrict__ hloc, float* __restrict__ y)
{
    const int b = blockIdx.z;
    const int c = blockIdx.x;
    const int e = blockIdx.y * 4 + (threadIdx.x >> 5);
    const int n = threadIdx.x & 31;
    const float Aen = -__expf(A_log[e * NST + n]);
    const float dpe = Dp[e];

    // inline prefix over chunks < c (coalesced 128B loads per 32-lane group)
    float hs = 0.f;
    {
        size_t idx = ((size_t)b * NC * ED + e) * NST + n;
        for (int cc = 0; cc < c; ++cc) {
            hs = fmaf(aprod[idx], hs, hloc[idx]);
            idx += (size_t)ED * NST;
        }
    }
    const size_t base = (size_t)b * Lseq + (size_t)c * LC;
    for (int l = 0; l < LC; ++l) {
        const size_t tok = base + l;
        const float de  = delta[tok * ED + e];
        const float Bn  = Bv[tok * NST + n];
        const float Cn  = Cv[tok * NST + n];
        const float xce = xc[tok * ED + e];
        const float a = __expf(de * Aen);
        hs = fmaf(a, hs, de * Bn * xce);
        float p = hs * Cn;
        #pragma unroll
        for (int off = 16; off; off >>= 1) p += __shfl_xor(p, off, 32);
        if (n == 0) {
            const float zi = zb[tok * ED + e];
            y[tok * ED + e] = (p + dpe * xce) * (zi * sigf(zi));
        }
    }
}

// ---------------- K5: last layer head: y(L-1) from hend, then fc dot -> logits
__global__ __launch_bounds__(128) void k_final_last(
    const float* __restrict__ hend, const float* __restrict__ Cv,
    const float* __restrict__ xc, const float* __restrict__ zb,
    const float* __restrict__ Dp, const float* __restrict__ fcw,
    const float* __restrict__ fcb, float* __restrict__ out)
{
    const int b = blockIdx.x;
    const int e = threadIdx.x;       // 0..127
    const size_t tok = (size_t)b * Lseq + (Lseq - 1);
    const float* hp = hend + (size_t)b * (ED * NST) + e * NST;
    const float* cp = Cv + tok * NST;
    float p = 0.f;
    #pragma unroll
    for (int n = 0; n < NST; ++n) p = fmaf(hp[n], cp[n], p);
    const float xce = xc[tok * ED + e];
    const float zi  = zb[tok * ED + e];
    float val = (p + Dp[e] * xce) * (zi * sigf(zi)) * fcw[e];
    __shared__ float sred[2];
    #pragma unroll
    for (int off = 32; off; off >>= 1) val += __shfl_xor(val, off, 64);
    if ((threadIdx.x & 63) == 0) sred[threadIdx.x >> 6] = val;
    __syncthreads();
    if (threadIdx.x == 0) out[b] = sred[0] + sred[1] + fcb[0];
}

extern "C" void kernel_launch(void* const* d_in, const int* in_sizes, int n_in,
                              void* d_out, int out_size, void* d_ws, size_t ws_size,
                              hipStream_t stream)
{
    const float* x         = (const float*)d_in[0];
    const float* in_w      = (const float*)d_in[1];
    const float* in_b      = (const float*)d_in[2];
    const float* conv_w    = (const float*)d_in[3];
    const float* conv_b    = (const float*)d_in[4];
    const float* xproj_w   = (const float*)d_in[5];
    const float* dtproj_w  = (const float*)d_in[6];
    const float* dtproj_b  = (const float*)d_in[7];
    const float* A_log     = (const float*)d_in[8];
    const float* Dp        = (const float*)d_in[9];
    const float* outproj_w = (const float*)d_in[10];
    const float* outproj_b = (const float*)d_in[11];
    const float* norm_w    = (const float*)d_in[12];
    const float* fc_w      = (const float*)d_in[13];
    const float* fc_b      = (const float*)d_in[14];

    const size_t TOK = (size_t)BSZ * Lseq;
    float* ws = (float*)d_ws;
    float* h0    = ws; ws += TOK * DM;
    float* h1    = ws; ws += TOK * DM;
    float* xin   = ws; ws += TOK * ED;   // reused as y after the scan
    float* zbuf  = ws; ws += TOK * ED;
    float* xc    = ws; ws += TOK * ED;
    float* dlt   = ws; ws += TOK * ED;
    float* Bv    = ws; ws += TOK * NST;
    float* Cv    = ws; ws += TOK * NST;
    float* aprod = ws; ws += (size_t)BSZ * NC * ED * NST;
    float* hloc  = ws; ws += (size_t)BSZ * NC * ED * NST;
    float* hend  = ws; ws += (size_t)BSZ * ED * NST;

    const float* hres = x;               // residual stream input for current layer
    float* hbufs[2] = { h0, h1 };

    for (int i = 0; i < NLAYERS; ++i) {
        const int last = (i == NLAYERS - 1);
        if (i == 0) {
            k_rms_inproj<<<(int)TOK, 256, 0, stream>>>(
                x, in_w, in_b, norm_w, xin, zbuf);
        } else {
            float* hout = hbufs[i & 1];
            k_fused_layer<<<(int)TOK, 256, 0, stream>>>(
                xin /* y of prev layer */,
                outproj_w + (size_t)(i - 1) * DM * ED,
                outproj_b + (size_t)(i - 1) * DM,
                hres, norm_w + (size_t)i * DM,
                in_w + (size_t)i * 2 * ED * DM, in_b + (size_t)i * 2 * ED,
                hout, xin, zbuf);
            hres = hout;
        }
        k_conv_proj<<<(int)(TOK / 2), 256, 0, stream>>>(
            xin, conv_w + (size_t)i * ED * DCONVK, conv_b + (size_t)i * ED,
            xproj_w + (size_t)i * (DTRANK + 2 * NST) * ED,
            dtproj_w + (size_t)i * ED * DTRANK, dtproj_b + (size_t)i * ED,
            xc, dlt, Bv, Cv);
        const float* Alog_i = A_log + (size_t)i * ED * NST;
        k_scan_local<<<dim3(NC, ED / 4, BSZ), 128, 0, stream>>>(
            dlt, Bv, xc, Alog_i, aprod, hloc);
        if (!last) {
            k_scan_y<<<dim3(NC, ED / 4, BSZ), 128, 0, stream>>>(
                dlt, Bv, Cv, xc, zbuf, Alog_i, Dp + (size_t)i * ED,
                aprod, hloc, xin);
        } else {
            k_scan_combine<<<(BSZ * ED * NST) / 256, 256, 0, stream>>>(
                aprod, hloc, hend);
            k_final_last<<<BSZ, 128, 0, stream>>>(
                hend, Cv, xc, zbuf, Dp + (size_t)i * ED, fc_w, fc_b, (float*)d_out);
        }
    }
}

// Round 4
// 741.190 us; speedup vs baseline: 9.3527x; 1.1599x over previous
//
#include <hip/hip_runtime.h>
#include <math.h>

#define BSZ 4
#define Lseq 2048
#define DM 64
#define ED 128
#define NST 32
#define DCONVK 16
#define NLAYERS 4
#define DTRANK 4
#define EPSV 1e-5f
#define NC 32                 // chunks along L for the scan
#define LC (Lseq / NC)        // 64 steps per chunk
#define TT 16                 // tokens per block in k_layer_gemm
#define TT2 32                // tokens per block in k_conv_proj

__device__ __forceinline__ float sigf(float x) { return 1.0f / (1.0f + __expf(-x)); }
__device__ __forceinline__ float hsum4(float4 a) { return (a.x + a.y) + (a.z + a.w); }

// ---------------- K_A: [outproj(prev y) + residual] + rmsnorm + inproj, 16 tokens/block
// has_out==0 (layer 0): skip outproj, h comes straight from hin (= x).
// y aliases the xin buffer; reads (own tile only) complete before xin writes.
__global__ __launch_bounds__(256) void k_layer_gemm(
    const float* __restrict__ y, const float* __restrict__ ow,
    const float* __restrict__ ob, const float* __restrict__ hin,
    const float* __restrict__ norm_w, const float* __restrict__ in_w,
    const float* __restrict__ in_b, float* __restrict__ hout,
    float* __restrict__ xin, float* __restrict__ zb, int has_out)
{
    const int t0 = blockIdx.x * TT;
    const int tid = threadIdx.x;
    const int lane = tid & 63;
    const int wv = tid >> 6;              // wave 0..3 -> tokens [wv*4, wv*4+4)
    __shared__ __align__(16) float ys[TT][ED];
    __shared__ __align__(16) float hn[TT][DM];

    float hval[4];
    const float nw = norm_w[lane];

    if (has_out) {
        // stage y tile (coalesced float4)
        {
            const float4* src = (const float4*)(y + (size_t)t0 * ED);
            float4* dst = (float4*)&ys[0][0];
            #pragma unroll
            for (int i = 0; i < (TT * ED / 4) / 256; ++i)
                dst[tid + i * 256] = src[tid + i * 256];
        }
        __syncthreads();
        // outproj: thread owns d=lane, tokens wv*4..+4, full k=128 in 2 passes
        float4 acc[4];
        #pragma unroll
        for (int j = 0; j < 4; ++j) acc[j] = make_float4(0.f, 0.f, 0.f, 0.f);
        #pragma unroll
        for (int p = 0; p < 2; ++p) {
            float4 w4[16];
            const float4* wr = (const float4*)(ow + lane * ED + p * 64);
            #pragma unroll
            for (int i = 0; i < 16; ++i) w4[i] = wr[i];
            #pragma unroll
            for (int j = 0; j < 4; ++j) {
                const float4* yv = (const float4*)&ys[wv * 4 + j][p * 64];
                #pragma unroll
                for (int i = 0; i < 16; ++i) {
                    float4 hv = yv[i];
                    acc[j].x = fmaf(hv.x, w4[i].x, acc[j].x);
                    acc[j].y = fmaf(hv.y, w4[i].y, acc[j].y);
                    acc[j].z = fmaf(hv.z, w4[i].z, acc[j].z);
                    acc[j].w = fmaf(hv.w, w4[i].w, acc[j].w);
                }
            }
        }
        const float obd = ob[lane];
        #pragma unroll
        for (int j = 0; j < 4; ++j) {
            const int tok = t0 + wv * 4 + j;
            hval[j] = hsum4(acc[j]) + obd + hin[(size_t)tok * DM + lane];
            hout[(size_t)tok * DM + lane] = hval[j];
        }
    } else {
        #pragma unroll
        for (int j = 0; j < 4; ++j)
            hval[j] = hin[(size_t)(t0 + wv * 4 + j) * DM + lane];
    }

    // rmsnorm (in-register butterfly over the 64 lanes = the 64 d's)
    #pragma unroll
    for (int j = 0; j < 4; ++j) {
        float ss = hval[j] * hval[j];
        #pragma unroll
        for (int off = 32; off; off >>= 1) ss += __shfl_xor(ss, off, 64);
        const float sc = rsqrtf(ss * (1.0f / DM) + EPSV);
        hn[wv * 4 + j][lane] = hval[j] * sc * nw;
    }
    __syncthreads();

    // inproj: thread owns output channel e=tid (0..255), all 16 tokens, k=64
    {
        float4 w4[16];
        const float4* wr = (const float4*)(in_w + tid * DM);
        #pragma unroll
        for (int i = 0; i < 16; ++i) w4[i] = wr[i];
        const float bias = in_b[tid];
        #pragma unroll 4
        for (int tok = 0; tok < TT; ++tok) {
            const float4* hv4 = (const float4*)&hn[tok][0];
            float4 a4 = make_float4(0.f, 0.f, 0.f, 0.f);
            #pragma unroll
            for (int i = 0; i < 16; ++i) {
                float4 hv = hv4[i];
                a4.x = fmaf(hv.x, w4[i].x, a4.x);
                a4.y = fmaf(hv.y, w4[i].y, a4.y);
                a4.z = fmaf(hv.z, w4[i].z, a4.z);
                a4.w = fmaf(hv.w, w4[i].w, a4.w);
            }
            const float r = bias + hsum4(a4);
            if (tid < ED) xin[(size_t)(t0 + tok) * ED + tid] = r;
            else          zb[(size_t)(t0 + tok) * ED + (tid - ED)] = r;
        }
    }
}

// ---------------- K_B: causal dwconv + silu ; xproj ; dtproj+softplus — 32 tokens/block
__global__ __launch_bounds__(256) void k_conv_proj(
    const float* __restrict__ xin, const float* __restrict__ conv_w,
    const float* __restrict__ conv_b, const float* __restrict__ xproj_w,
    const float* __restrict__ dtproj_w, const float* __restrict__ dtproj_b,
    float* __restrict__ xc_out, float* __restrict__ delta_out,
    float* __restrict__ Bout, float* __restrict__ Cout)
{
    const int blk = blockIdx.x;             // BSZ * (Lseq/TT2) blocks
    const int b   = blk >> 6;               // Lseq/TT2 = 64
    const int ch  = blk & 63;
    const int l0  = ch * TT2;
    const size_t t0 = (size_t)b * Lseq + l0;
    const int tid = threadIdx.x;
    __shared__ __align__(16) float xs[(TT2 + DCONVK - 1) * ED];   // rows l0-15 .. l0+31
    __shared__ __align__(16) float xcs[TT2][132];                  // padded rows
    __shared__ float dts[TT2][DTRANK];

    // stage xin rows (zero-fill before sequence start)
    for (int idx = tid; idx < (TT2 + DCONVK - 1) * ED; idx += 256) {
        const int row = idx >> 7;
        const int lrow = l0 - (DCONVK - 1) + row;
        float v = 0.f;
        if (lrow >= 0) v = xin[((size_t)b * Lseq + lrow) * ED + (idx & 127)];
        xs[idx] = v;
    }
    __syncthreads();

    const int e = tid & 127, half = tid >> 7;   // half: tokens [half*16, half*16+16)
    // conv: register sliding window
    {
        float w[DCONVK];
        {
            const float4* cw = (const float4*)(conv_w + e * DCONVK);
            #pragma unroll
            for (int i = 0; i < 4; ++i) {
                float4 c = cw[i];
                w[i*4+0] = c.x; w[i*4+1] = c.y; w[i*4+2] = c.z; w[i*4+3] = c.w;
            }
        }
        const float cb = conv_b[e];
        float xw[DCONVK - 1];
        #pragma unroll
        for (int k = 0; k < DCONVK - 1; ++k) xw[k] = xs[(half * 16 + k) * ED + e];
        #pragma unroll
        for (int j = 0; j < 16; ++j) {
            const float xnew = xs[(half * 16 + j + DCONVK - 1) * ED + e];
            float acc = fmaf(xnew, w[DCONVK - 1], cb);
            #pragma unroll
            for (int k = 0; k < DCONVK - 1; ++k) acc = fmaf(xw[k], w[k], acc);
            #pragma unroll
            for (int k = 0; k < DCONVK - 2; ++k) xw[k] = xw[k + 1];
            xw[DCONVK - 2] = xnew;
            const float xcv = acc * sigf(acc);
            xcs[half * 16 + j][e] = xcv;
            xc_out[(t0 + half * 16 + j) * ED + e] = xcv;
        }
    }
    __syncthreads();

    // xproj: wave wv handles tokens [wv*8, wv*8+8); lane = dbc row (0..63 primary)
    {
        const int wv = tid >> 6, lane = tid & 63;
        float4 acc[8];
        #pragma unroll
        for (int j = 0; j < 8; ++j) acc[j] = make_float4(0.f, 0.f, 0.f, 0.f);
        #pragma unroll
        for (int p = 0; p < 2; ++p) {
            float4 w4[16];
            const float4* wr = (const float4*)(xproj_w + lane * ED + p * 64);
            #pragma unroll
            for (int i = 0; i < 16; ++i) w4[i] = wr[i];
            #pragma unroll
            for (int j = 0; j < 8; ++j) {
                const float4* yv = (const float4*)&xcs[wv * 8 + j][p * 64];
                #pragma unroll
                for (int i = 0; i < 16; ++i) {
                    float4 hv = yv[i];
                    acc[j].x = fmaf(hv.x, w4[i].x, acc[j].x);
                    acc[j].y = fmaf(hv.y, w4[i].y, acc[j].y);
                    acc[j].z = fmaf(hv.z, w4[i].z, acc[j].z);
                    acc[j].w = fmaf(hv.w, w4[i].w, acc[j].w);
                }
            }
        }
        #pragma unroll
        for (int j = 0; j < 8; ++j) {
            const int tok = wv * 8 + j;
            const float v = hsum4(acc[j]);
            if (lane < DTRANK)            dts[tok][lane] = v;
            else if (lane < DTRANK + NST) Bout[(t0 + tok) * NST + (lane - DTRANK)] = v;
            else                          Cout[(t0 + tok) * NST + (lane - DTRANK - NST)] = v;
        }
        // leftover rows 64..67 (C idx 28..31): lane -> (r', tok', kslice)
        {
            const int r4  = 64 + (lane >> 4);
            const int tok = wv * 8 + ((lane >> 1) & 7);
            const int ks  = lane & 1;
            const float4* wr = (const float4*)(xproj_w + r4 * ED + ks * 64);
            const float4* yv = (const float4*)&xcs[tok][ks * 64];
            float4 a4 = make_float4(0.f, 0.f, 0.f, 0.f);
            #pragma unroll
            for (int i = 0; i < 16; ++i) {
                float4 hv = yv[i]; float4 wv4 = wr[i];
                a4.x = fmaf(hv.x, wv4.x, a4.x);
                a4.y = fmaf(hv.y, wv4.y, a4.y);
                a4.z = fmaf(hv.z, wv4.z, a4.z);
                a4.w = fmaf(hv.w, wv4.w, a4.w);
            }
            float v = hsum4(a4);
            v += __shfl_xor(v, 1, 64);
            if (ks == 0) Cout[(t0 + tok) * NST + (r4 - DTRANK - NST)] = v;
        }
    }
    __syncthreads();

    // dtproj + softplus: thread (e, half) -> 16 tokens
    {
        const float* dwp = dtproj_w + e * DTRANK;
        const float4 dwv = *(const float4*)dwp;
        const float bias = dtproj_b[e];
        #pragma unroll
        for (int j = 0; j < 16; ++j) {
            const int tok = half * 16 + j;
            float a = bias;
            a = fmaf(dts[tok][0], dwv.x, a);
            a = fmaf(dts[tok][1], dwv.y, a);
            a = fmaf(dts[tok][2], dwv.z, a);
            a = fmaf(dts[tok][3], dwv.w, a);
            const float sp = fmaxf(a, 0.f) + log1pf(__expf(-fabsf(a)));
            delta_out[(t0 + tok) * ED + e] = sp;
        }
    }
}

// ---------------- K3a: per-chunk local scan (from zero state). block=128: 4 e-ch x 32 n.
__global__ __launch_bounds__(128) void k_scan_local(
    const float* __restrict__ delta, const float* __restrict__ Bv,
    const float* __restrict__ xc, const float* __restrict__ A_log,
    float* __restrict__ aprod, float* __restrict__ hloc)
{
    const int b = blockIdx.z;
    const int c = blockIdx.x;
    const int e = blockIdx.y * 4 + (threadIdx.x >> 5);
    const int n = threadIdx.x & 31;
    const float Aen = -__expf(A_log[e * NST + n]);
    float hs = 0.f, ap = 1.f;
    const size_t base = (size_t)b * Lseq + (size_t)c * LC;
    #pragma unroll 4
    for (int l = 0; l < LC; ++l) {
        const size_t tok = base + l;
        const float de  = delta[tok * ED + e];
        const float Bn  = Bv[tok * NST + n];
        const float xce = xc[tok * ED + e];
        const float a = __expf(de * Aen);
        hs = fmaf(a, hs, de * Bn * xce);
        ap *= a;
    }
    const size_t idx = (((size_t)b * NC + c) * ED + e) * NST + n;
    aprod[idx] = ap;
    hloc[idx]  = hs;
}

// ---------------- K3b (last layer only): chunk combine -> hend
__global__ __launch_bounds__(256) void k_scan_combine(
    const float* __restrict__ aprod, const float* __restrict__ hloc,
    float* __restrict__ hend)
{
    const int tid = blockIdx.x * 256 + threadIdx.x;   // 0..16383
    const int b = tid >> 12;                          // ED*NST = 4096
    const int en = tid & 4095;
    size_t idx = (size_t)b * NC * (ED * NST) + en;
    float h = 0.f;
    #pragma unroll 4
    for (int c = 0; c < NC; ++c) {
        h = fmaf(aprod[idx], h, hloc[idx]);
        idx += ED * NST;
    }
    hend[(size_t)b * (ED * NST) + en] = h;
}

// ---------------- K3c: per-chunk scan with inline chunk-prefix, emit y (non-last layers)
__global__ __launch_bounds__(128) void k_scan_y(
    const float* __restrict__ delta, const float* __restrict__ Bv,
    const float* __restrict__ Cv, const float* __restrict__ xc,
    const float* __restrict__ zb, const float* __restrict__ A_log,
    const float* __restrict__ Dp, const float* __restrict__ aprod,
    const float* __restrict__ hloc, float* __restrict__ y)
{
    const int b = blockIdx.z;
    const int c = blockIdx.x;
    const int e = blockIdx.y * 4 + (threadIdx.x >> 5);
    const int n = threadIdx.x & 31;
    const float Aen = -__expf(A_log[e * NST + n]);
    const float dpe = Dp[e];

    float hs = 0.f;
    {
        size_t idx = ((size_t)b * NC * ED + e) * NST + n;
        for (int cc = 0; cc < c; ++cc) {
            hs = fmaf(aprod[idx], hs, hloc[idx]);
            idx += (size_t)ED * NST;
        }
    }
    const size_t base = (size_t)b * Lseq + (size_t)c * LC;
    for (int l = 0; l < LC; ++l) {
        const size_t tok = base + l;
        const float de  = delta[tok * ED + e];
        const float Bn  = Bv[tok * NST + n];
        const float Cn  = Cv[tok * NST + n];
        const float xce = xc[tok * ED + e];
        const float a = __expf(de * Aen);
        hs = fmaf(a, hs, de * Bn * xce);
        float p = hs * Cn;
        #pragma unroll
        for (int off = 16; off; off >>= 1) p += __shfl_xor(p, off, 32);
        if (n == 0) {
            const float zi = zb[tok * ED + e];
            y[tok * ED + e] = (p + dpe * xce) * (zi * sigf(zi));
        }
    }
}

// ---------------- K5: last layer head: y(L-1) from hend, then fc dot -> logits
__global__ __launch_bounds__(128) void k_final_last(
    const float* __restrict__ hend, const float* __restrict__ Cv,
    const float* __restrict__ xc, const float* __restrict__ zb,
    const float* __restrict__ Dp, const float* __restrict__ fcw,
    const float* __restrict__ fcb, float* __restrict__ out)
{
    const int b = blockIdx.x;
    const int e = threadIdx.x;       // 0..127
    const size_t tok = (size_t)b * Lseq + (Lseq - 1);
    const float* hp = hend + (size_t)b * (ED * NST) + e * NST;
    const float* cp = Cv + tok * NST;
    float p = 0.f;
    #pragma unroll
    for (int n = 0; n < NST; ++n) p = fmaf(hp[n], cp[n], p);
    const float xce = xc[tok * ED + e];
    const float zi  = zb[tok * ED + e];
    float val = (p + Dp[e] * xce) * (zi * sigf(zi)) * fcw[e];
    __shared__ float sred[2];
    #pragma unroll
    for (int off = 32; off; off >>= 1) val += __shfl_xor(val, off, 64);
    if ((threadIdx.x & 63) == 0) sred[threadIdx.x >> 6] = val;
    __syncthreads();
    if (threadIdx.x == 0) out[b] = sred[0] + sred[1] + fcb[0];
}

extern "C" void kernel_launch(void* const* d_in, const int* in_sizes, int n_in,
                              void* d_out, int out_size, void* d_ws, size_t ws_size,
                              hipStream_t stream)
{
    const float* x         = (const float*)d_in[0];
    const float* in_w      = (const float*)d_in[1];
    const float* in_b      = (const float*)d_in[2];
    const float* conv_w    = (const float*)d_in[3];
    const float* conv_b    = (const float*)d_in[4];
    const float* xproj_w   = (const float*)d_in[5];
    const float* dtproj_w  = (const float*)d_in[6];
    const float* dtproj_b  = (const float*)d_in[7];
    const float* A_log     = (const float*)d_in[8];
    const float* Dp        = (const float*)d_in[9];
    const float* outproj_w = (const float*)d_in[10];
    const float* outproj_b = (const float*)d_in[11];
    const float* norm_w    = (const float*)d_in[12];
    const float* fc_w      = (const float*)d_in[13];
    const float* fc_b      = (const float*)d_in[14];

    const size_t TOK = (size_t)BSZ * Lseq;
    float* ws = (float*)d_ws;
    float* h0    = ws; ws += TOK * DM;
    float* h1    = ws; ws += TOK * DM;
    float* xin   = ws; ws += TOK * ED;   // reused as y after the scan
    float* zbuf  = ws; ws += TOK * ED;
    float* xc    = ws; ws += TOK * ED;
    float* dlt   = ws; ws += TOK * ED;
    float* Bv    = ws; ws += TOK * NST;
    float* Cv    = ws; ws += TOK * NST;
    float* aprod = ws; ws += (size_t)BSZ * NC * ED * NST;
    float* hloc  = ws; ws += (size_t)BSZ * NC * ED * NST;
    float* hend  = ws; ws += (size_t)BSZ * ED * NST;

    const float* hres = x;               // residual stream input for current layer
    float* hbufs[2] = { h0, h1 };

    for (int i = 0; i < NLAYERS; ++i) {
        const int last = (i == NLAYERS - 1);
        if (i == 0) {
            k_layer_gemm<<<(int)(TOK / TT), 256, 0, stream>>>(
                nullptr, nullptr, nullptr, x, norm_w, in_w, in_b,
                nullptr, xin, zbuf, 0);
        } else {
            float* hout = hbufs[i & 1];
            k_layer_gemm<<<(int)(TOK / TT), 256, 0, stream>>>(
                xin /* y of prev layer */,
                outproj_w + (size_t)(i - 1) * DM * ED,
                outproj_b + (size_t)(i - 1) * DM,
                hres, norm_w + (size_t)i * DM,
                in_w + (size_t)i * 2 * ED * DM, in_b + (size_t)i * 2 * ED,
                hout, xin, zbuf, 1);
            hres = hout;
        }
        k_conv_proj<<<(int)(TOK / TT2), 256, 0, stream>>>(
            xin, conv_w + (size_t)i * ED * DCONVK, conv_b + (size_t)i * ED,
            xproj_w + (size_t)i * (DTRANK + 2 * NST) * ED,
            dtproj_w + (size_t)i * ED * DTRANK, dtproj_b + (size_t)i * ED,
            xc, dlt, Bv, Cv);
        const float* Alog_i = A_log + (size_t)i * ED * NST;
        k_scan_local<<<dim3(NC, ED / 4, BSZ), 128, 0, stream>>>(
            dlt, Bv, xc, Alog_i, aprod, hloc);
        if (!last) {
            k_scan_y<<<dim3(NC, ED / 4, BSZ), 128, 0, stream>>>(
                dlt, Bv, Cv, xc, zbuf, Alog_i, Dp + (size_t)i * ED,
                aprod, hloc, xin);
        } else {
            k_scan_combine<<<(BSZ * ED * NST) / 256, 256, 0, stream>>>(
                aprod, hloc, hend);
            k_final_last<<<BSZ, 128, 0, stream>>>(
                hend, Cv, xc, zbuf, Dp + (size_t)i * ED, fc_w, fc_b, (float*)d_out);
        }
    }
}

// Round 5
// 536.153 us; speedup vs baseline: 12.9294x; 1.3824x over previous
//
#include <hip/hip_runtime.h>
#include <math.h>

#define BSZ 4
#define Lseq 2048
#define DM 64
#define ED 128
#define NST 32
#define DCONVK 16
#define NLAYERS 4
#define DTRANK 4
#define EPSV 1e-5f
#define NC 32                 // chunks along L for the scan
#define LC (Lseq / NC)        // 64 steps per chunk
#define TT 16                 // tokens per block in k_layer_gemm
#define TT2 16                // tokens per block in k_conv_proj

__device__ __forceinline__ float sigf(float x) { return 1.0f / (1.0f + __expf(-x)); }
__device__ __forceinline__ float hsum4(float4 a) { return (a.x + a.y) + (a.z + a.w); }

// ---------------- K_A: [outproj(prev y) + residual] + rmsnorm + inproj, 16 tokens/block
__global__ __launch_bounds__(256) void k_layer_gemm(
    const float* __restrict__ y, const float* __restrict__ ow,
    const float* __restrict__ ob, const float* __restrict__ hin,
    const float* __restrict__ norm_w, const float* __restrict__ in_w,
    const float* __restrict__ in_b, float* __restrict__ hout,
    float* __restrict__ xin, float* __restrict__ zb, int has_out)
{
    const int t0 = blockIdx.x * TT;
    const int tid = threadIdx.x;
    const int lane = tid & 63;
    const int wv = tid >> 6;              // wave 0..3 -> tokens [wv*4, wv*4+4)
    __shared__ __align__(16) float ys[TT][ED];
    __shared__ __align__(16) float hn[TT][DM];

    float hval[4];
    const float nw = norm_w[lane];

    if (has_out) {
        {
            const float4* src = (const float4*)(y + (size_t)t0 * ED);
            float4* dst = (float4*)&ys[0][0];
            #pragma unroll
            for (int i = 0; i < (TT * ED / 4) / 256; ++i)
                dst[tid + i * 256] = src[tid + i * 256];
        }
        __syncthreads();
        float4 acc[4];
        #pragma unroll
        for (int j = 0; j < 4; ++j) acc[j] = make_float4(0.f, 0.f, 0.f, 0.f);
        #pragma unroll
        for (int p = 0; p < 2; ++p) {
            float4 w4[16];
            const float4* wr = (const float4*)(ow + lane * ED + p * 64);
            #pragma unroll
            for (int i = 0; i < 16; ++i) w4[i] = wr[i];
            #pragma unroll
            for (int j = 0; j < 4; ++j) {
                const float4* yv = (const float4*)&ys[wv * 4 + j][p * 64];
                #pragma unroll
                for (int i = 0; i < 16; ++i) {
                    float4 hv = yv[i];
                    acc[j].x = fmaf(hv.x, w4[i].x, acc[j].x);
                    acc[j].y = fmaf(hv.y, w4[i].y, acc[j].y);
                    acc[j].z = fmaf(hv.z, w4[i].z, acc[j].z);
                    acc[j].w = fmaf(hv.w, w4[i].w, acc[j].w);
                }
            }
        }
        const float obd = ob[lane];
        #pragma unroll
        for (int j = 0; j < 4; ++j) {
            const int tok = t0 + wv * 4 + j;
            hval[j] = hsum4(acc[j]) + obd + hin[(size_t)tok * DM + lane];
            hout[(size_t)tok * DM + lane] = hval[j];
        }
    } else {
        #pragma unroll
        for (int j = 0; j < 4; ++j)
            hval[j] = hin[(size_t)(t0 + wv * 4 + j) * DM + lane];
    }

    #pragma unroll
    for (int j = 0; j < 4; ++j) {
        float ss = hval[j] * hval[j];
        #pragma unroll
        for (int off = 32; off; off >>= 1) ss += __shfl_xor(ss, off, 64);
        const float sc = rsqrtf(ss * (1.0f / DM) + EPSV);
        hn[wv * 4 + j][lane] = hval[j] * sc * nw;
    }
    __syncthreads();

    {
        float4 w4[16];
        const float4* wr = (const float4*)(in_w + tid * DM);
        #pragma unroll
        for (int i = 0; i < 16; ++i) w4[i] = wr[i];
        const float bias = in_b[tid];
        #pragma unroll 4
        for (int tok = 0; tok < TT; ++tok) {
            const float4* hv4 = (const float4*)&hn[tok][0];
            float4 a4 = make_float4(0.f, 0.f, 0.f, 0.f);
            #pragma unroll
            for (int i = 0; i < 16; ++i) {
                float4 hv = hv4[i];
                a4.x = fmaf(hv.x, w4[i].x, a4.x);
                a4.y = fmaf(hv.y, w4[i].y, a4.y);
                a4.z = fmaf(hv.z, w4[i].z, a4.z);
                a4.w = fmaf(hv.w, w4[i].w, a4.w);
            }
            const float r = bias + hsum4(a4);
            if (tid < ED) xin[(size_t)(t0 + tok) * ED + tid] = r;
            else          zb[(size_t)(t0 + tok) * ED + (tid - ED)] = r;
        }
    }
}

// ---------------- K_B: causal dwconv + silu ; xproj ; dtproj+softplus — 16 tokens/block
__global__ __launch_bounds__(256) void k_conv_proj(
    const float* __restrict__ xin, const float* __restrict__ conv_w,
    const float* __restrict__ conv_b, const float* __restrict__ xproj_w,
    const float* __restrict__ dtproj_w, const float* __restrict__ dtproj_b,
    float* __restrict__ xc_out, float* __restrict__ delta_out,
    float* __restrict__ Bout, float* __restrict__ Cout)
{
    const int blk = blockIdx.x;             // BSZ * (Lseq/TT2) blocks
    const int b   = blk >> 7;               // Lseq/TT2 = 128
    const int ch  = blk & 127;
    const int l0  = ch * TT2;
    const size_t t0 = (size_t)b * Lseq + l0;
    const int tid = threadIdx.x;
    __shared__ __align__(16) float xs[(TT2 + DCONVK - 1) * ED];   // rows l0-15 .. l0+15
    __shared__ __align__(16) float xcs[TT2][ED];
    __shared__ float dts[TT2][DTRANK];

    // stage xin rows (float4, zero-fill before sequence start)
    {
        const int NV = (TT2 + DCONVK - 1) * ED / 4;   // 992
        for (int idx4 = tid; idx4 < NV; idx4 += 256) {
            const int row = idx4 >> 5;
            const int lrow = l0 - (DCONVK - 1) + row;
            float4 v = make_float4(0.f, 0.f, 0.f, 0.f);
            if (lrow >= 0)
                v = ((const float4*)(xin + ((size_t)b * Lseq + lrow) * ED))[idx4 & 31];
            ((float4*)xs)[idx4] = v;
        }
    }
    __syncthreads();

    const int e = tid & 127, half = tid >> 7;   // half: tokens [half*8, half*8+8)
    // conv: direct LDS reads (conflict-free: lane->e maps to distinct banks)
    {
        float w[DCONVK];
        {
            const float4* cw = (const float4*)(conv_w + e * DCONVK);
            #pragma unroll
            for (int i = 0; i < 4; ++i) {
                float4 c = cw[i];
                w[i*4+0] = c.x; w[i*4+1] = c.y; w[i*4+2] = c.z; w[i*4+3] = c.w;
            }
        }
        const float cb = conv_b[e];
        #pragma unroll
        for (int j = 0; j < 8; ++j) {
            const int tok = half * 8 + j;
            float acc = cb;
            #pragma unroll
            for (int k = 0; k < DCONVK; ++k)
                acc = fmaf(xs[(tok + k) * ED + e], w[k], acc);
            const float xcv = acc * sigf(acc);
            xcs[tok][e] = xcv;
            xc_out[(t0 + tok) * ED + e] = xcv;
        }
    }
    __syncthreads();

    // xproj: wave wv -> tokens [wv*4, wv*4+4); lane = dbc row 0..63
    {
        const int wv = tid >> 6, lane = tid & 63;
        float4 acc[4];
        #pragma unroll
        for (int j = 0; j < 4; ++j) acc[j] = make_float4(0.f, 0.f, 0.f, 0.f);
        #pragma unroll
        for (int p = 0; p < 2; ++p) {
            float4 w4[16];
            const float4* wr = (const float4*)(xproj_w + lane * ED + p * 64);
            #pragma unroll
            for (int i = 0; i < 16; ++i) w4[i] = wr[i];
            #pragma unroll
            for (int j = 0; j < 4; ++j) {
                const float4* yv = (const float4*)&xcs[wv * 4 + j][p * 64];
                #pragma unroll
                for (int i = 0; i < 16; ++i) {
                    float4 hv = yv[i];
                    acc[j].x = fmaf(hv.x, w4[i].x, acc[j].x);
                    acc[j].y = fmaf(hv.y, w4[i].y, acc[j].y);
                    acc[j].z = fmaf(hv.z, w4[i].z, acc[j].z);
                    acc[j].w = fmaf(hv.w, w4[i].w, acc[j].w);
                }
            }
        }
        #pragma unroll
        for (int j = 0; j < 4; ++j) {
            const int tok = wv * 4 + j;
            const float v = hsum4(acc[j]);
            if (lane < DTRANK)            dts[tok][lane] = v;
            else if (lane < DTRANK + NST) Bout[(t0 + tok) * NST + (lane - DTRANK)] = v;
            else                          Cout[(t0 + tok) * NST + (lane - DTRANK - NST)] = v;
        }
        // leftover rows 64..67 (C idx 28..31): lane = 16*toksub + 4*ks + ridx
        {
            const int ridx = lane & 3;
            const int ks   = (lane >> 2) & 3;
            const int tsub = lane >> 4;
            const int r4   = 64 + ridx;
            const int tok  = wv * 4 + tsub;
            const float4* wr = (const float4*)(xproj_w + r4 * ED + ks * 32);
            const float4* yv = (const float4*)&xcs[tok][ks * 32];
            float4 a4 = make_float4(0.f, 0.f, 0.f, 0.f);
            #pragma unroll
            for (int i = 0; i < 8; ++i) {
                float4 hv = yv[i]; float4 wv4 = wr[i];
                a4.x = fmaf(hv.x, wv4.x, a4.x);
                a4.y = fmaf(hv.y, wv4.y, a4.y);
                a4.z = fmaf(hv.z, wv4.z, a4.z);
                a4.w = fmaf(hv.w, wv4.w, a4.w);
            }
            float v = hsum4(a4);
            v += __shfl_xor(v, 4, 64);
            v += __shfl_xor(v, 8, 64);
            if (ks == 0) Cout[(t0 + tok) * NST + (r4 - DTRANK - NST)] = v;
        }
    }
    __syncthreads();

    // dtproj + softplus: thread (e, half) -> 8 tokens
    {
        const float4 dwv = *(const float4*)(dtproj_w + e * DTRANK);
        const float bias = dtproj_b[e];
        #pragma unroll
        for (int j = 0; j < 8; ++j) {
            const int tok = half * 8 + j;
            float a = bias;
            a = fmaf(dts[tok][0], dwv.x, a);
            a = fmaf(dts[tok][1], dwv.y, a);
            a = fmaf(dts[tok][2], dwv.z, a);
            a = fmaf(dts[tok][3], dwv.w, a);
            const float sp = fmaxf(a, 0.f) + log1pf(__expf(-fabsf(a)));
            delta_out[(t0 + tok) * ED + e] = sp;
        }
    }
}

// ---------------- K3a: per-chunk local scan (from zero state). block=128: 4 e-ch x 32 n.
__global__ __launch_bounds__(128) void k_scan_local(
    const float* __restrict__ delta, const float* __restrict__ Bv,
    const float* __restrict__ xc, const float* __restrict__ A_log,
    float* __restrict__ aprod, float* __restrict__ hloc)
{
    const int b = blockIdx.z;
    const int c = blockIdx.x;
    const int e = blockIdx.y * 4 + (threadIdx.x >> 5);
    const int n = threadIdx.x & 31;
    const float Aen = -__expf(A_log[e * NST + n]);
    float hs = 0.f, ap = 1.f;
    const size_t base = (size_t)b * Lseq + (size_t)c * LC;
    #pragma unroll 4
    for (int l = 0; l < LC; ++l) {
        const size_t tok = base + l;
        const float de  = delta[tok * ED + e];
        const float Bn  = Bv[tok * NST + n];
        const float xce = xc[tok * ED + e];
        const float a = __expf(de * Aen);
        hs = fmaf(a, hs, de * Bn * xce);
        ap *= a;
    }
    const size_t idx = (((size_t)b * NC + c) * ED + e) * NST + n;
    aprod[idx] = ap;
    hloc[idx]  = hs;
}

// ---------------- K3b (last layer only): chunk combine -> hend
__global__ __launch_bounds__(256) void k_scan_combine(
    const float* __restrict__ aprod, const float* __restrict__ hloc,
    float* __restrict__ hend)
{
    const int tid = blockIdx.x * 256 + threadIdx.x;   // 0..16383
    const int b = tid >> 12;                          // ED*NST = 4096
    const int en = tid & 4095;
    size_t idx = (size_t)b * NC * (ED * NST) + en;
    float h = 0.f;
    #pragma unroll 4
    for (int c = 0; c < NC; ++c) {
        h = fmaf(aprod[idx], h, hloc[idx]);
        idx += ED * NST;
    }
    hend[(size_t)b * (ED * NST) + en] = h;
}

// ---------------- K3c: per-chunk scan with inline chunk-prefix, emit y (non-last layers)
__global__ __launch_bounds__(128) void k_scan_y(
    const float* __restrict__ delta, const float* __restrict__ Bv,
    const float* __restrict__ Cv, const float* __restrict__ xc,
    const float* __restrict__ zb, const float* __restrict__ A_log,
    const float* __restrict__ Dp, const float* __restrict__ aprod,
    const float* __restrict__ hloc, float* __restrict__ y)
{
    const int b = blockIdx.z;
    const int c = blockIdx.x;
    const int e = blockIdx.y * 4 + (threadIdx.x >> 5);
    const int n = threadIdx.x & 31;
    const float Aen = -__expf(A_log[e * NST + n]);
    const float dpe = Dp[e];

    float hs = 0.f;
    {
        size_t idx = ((size_t)b * NC * ED + e) * NST + n;
        for (int cc = 0; cc < c; ++cc) {
            hs = fmaf(aprod[idx], hs, hloc[idx]);
            idx += (size_t)ED * NST;
        }
    }
    const size_t base = (size_t)b * Lseq + (size_t)c * LC;
    for (int l = 0; l < LC; ++l) {
        const size_t tok = base + l;
        const float de  = delta[tok * ED + e];
        const float Bn  = Bv[tok * NST + n];
        const float Cn  = Cv[tok * NST + n];
        const float xce = xc[tok * ED + e];
        const float a = __expf(de * Aen);
        hs = fmaf(a, hs, de * Bn * xce);
        float p = hs * Cn;
        #pragma unroll
        for (int off = 16; off; off >>= 1) p += __shfl_xor(p, off, 32);
        if (n == 0) {
            const float zi = zb[tok * ED + e];
            y[tok * ED + e] = (p + dpe * xce) * (zi * sigf(zi));
        }
    }
}

// ---------------- K5: last layer head: y(L-1) from hend, then fc dot -> logits
__global__ __launch_bounds__(128) void k_final_last(
    const float* __restrict__ hend, const float* __restrict__ Cv,
    const float* __restrict__ xc, const float* __restrict__ zb,
    const float* __restrict__ Dp, const float* __restrict__ fcw,
    const float* __restrict__ fcb, float* __restrict__ out)
{
    const int b = blockIdx.x;
    const int e = threadIdx.x;       // 0..127
    const size_t tok = (size_t)b * Lseq + (Lseq - 1);
    const float* hp = hend + (size_t)b * (ED * NST) + e * NST;
    const float* cp = Cv + tok * NST;
    float p = 0.f;
    #pragma unroll
    for (int n = 0; n < NST; ++n) p = fmaf(hp[n], cp[n], p);
    const float xce = xc[tok * ED + e];
    const float zi  = zb[tok * ED + e];
    float val = (p + Dp[e] * xce) * (zi * sigf(zi)) * fcw[e];
    __shared__ float sred[2];
    #pragma unroll
    for (int off = 32; off; off >>= 1) val += __shfl_xor(val, off, 64);
    if ((threadIdx.x & 63) == 0) sred[threadIdx.x >> 6] = val;
    __syncthreads();
    if (threadIdx.x == 0) out[b] = sred[0] + sred[1] + fcb[0];
}

extern "C" void kernel_launch(void* const* d_in, const int* in_sizes, int n_in,
                              void* d_out, int out_size, void* d_ws, size_t ws_size,
                              hipStream_t stream)
{
    const float* x         = (const float*)d_in[0];
    const float* in_w      = (const float*)d_in[1];
    const float* in_b      = (const float*)d_in[2];
    const float* conv_w    = (const float*)d_in[3];
    const float* conv_b    = (const float*)d_in[4];
    const float* xproj_w   = (const float*)d_in[5];
    const float* dtproj_w  = (const float*)d_in[6];
    const float* dtproj_b  = (const float*)d_in[7];
    const float* A_log     = (const float*)d_in[8];
    const float* Dp        = (const float*)d_in[9];
    const float* outproj_w = (const float*)d_in[10];
    const float* outproj_b = (const float*)d_in[11];
    const float* norm_w    = (const float*)d_in[12];
    const float* fc_w      = (const float*)d_in[13];
    const float* fc_b      = (const float*)d_in[14];

    const size_t TOK = (size_t)BSZ * Lseq;
    float* ws = (float*)d_ws;
    float* h0    = ws; ws += TOK * DM;
    float* h1    = ws; ws += TOK * DM;
    float* xin   = ws; ws += TOK * ED;   // reused as y after the scan
    float* zbuf  = ws; ws += TOK * ED;
    float* xc    = ws; ws += TOK * ED;
    float* dlt   = ws; ws += TOK * ED;
    float* Bv    = ws; ws += TOK * NST;
    float* Cv    = ws; ws += TOK * NST;
    float* aprod = ws; ws += (size_t)BSZ * NC * ED * NST;
    float* hloc  = ws; ws += (size_t)BSZ * NC * ED * NST;
    float* hend  = ws; ws += (size_t)BSZ * ED * NST;

    const float* hres = x;               // residual stream input for current layer
    float* hbufs[2] = { h0, h1 };

    for (int i = 0; i < NLAYERS; ++i) {
        const int last = (i == NLAYERS - 1);
        if (i == 0) {
            k_layer_gemm<<<(int)(TOK / TT), 256, 0, stream>>>(
                nullptr, nullptr, nullptr, x, norm_w, in_w, in_b,
                nullptr, xin, zbuf, 0);
        } else {
            float* hout = hbufs[i & 1];
            k_layer_gemm<<<(int)(TOK / TT), 256, 0, stream>>>(
                xin /* y of prev layer */,
                outproj_w + (size_t)(i - 1) * DM * ED,
                outproj_b + (size_t)(i - 1) * DM,
                hres, norm_w + (size_t)i * DM,
                in_w + (size_t)i * 2 * ED * DM, in_b + (size_t)i * 2 * ED,
                hout, xin, zbuf, 1);
            hres = hout;
        }
        k_conv_proj<<<(int)(TOK / TT2), 256, 0, stream>>>(
            xin, conv_w + (size_t)i * ED * DCONVK, conv_b + (size_t)i * ED,
            xproj_w + (size_t)i * (DTRANK + 2 * NST) * ED,
            dtproj_w + (size_t)i * ED * DTRANK, dtproj_b + (size_t)i * ED,
            xc, dlt, Bv, Cv);
        const float* Alog_i = A_log + (size_t)i * ED * NST;
        k_scan_local<<<dim3(NC, ED / 4, BSZ), 128, 0, stream>>>(
            dlt, Bv, xc, Alog_i, aprod, hloc);
        if (!last) {
            k_scan_y<<<dim3(NC, ED / 4, BSZ), 128, 0, stream>>>(
                dlt, Bv, Cv, xc, zbuf, Alog_i, Dp + (size_t)i * ED,
                aprod, hloc, xin);
        } else {
            k_scan_combine<<<(BSZ * ED * NST) / 256, 256, 0, stream>>>(
                aprod, hloc, hend);
            k_final_last<<<BSZ, 128, 0, stream>>>(
                hend, Cv, xc, zbuf, Dp + (size_t)i * ED, fc_w, fc_b, (float*)d_out);
        }
    }
}

// Round 6
// 483.278 us; speedup vs baseline: 14.3440x; 1.1094x over previous
//
#include <hip/hip_runtime.h>
#include <math.h>

#define BSZ 4
#define Lseq 2048
#define DM 64
#define ED 128
#define NST 32
#define DCONVK 16
#define NLAYERS 4
#define DTRANK 4
#define EPSV 1e-5f
#define NC 64                 // chunks along L for the scan
#define LC (Lseq / NC)        // 32 steps per chunk
#define TT 16                 // tokens per block in k_layer_gemm
#define TT2 16                // tokens per block in k_conv_proj

__device__ __forceinline__ float sigf(float x) { return 1.0f / (1.0f + __expf(-x)); }
__device__ __forceinline__ float hsum4(float4 a) { return (a.x + a.y) + (a.z + a.w); }

// ---------------- K_A: [outproj(prev y) + residual] + rmsnorm + inproj, 16 tokens/block
__global__ __launch_bounds__(256) void k_layer_gemm(
    const float* __restrict__ y, const float* __restrict__ ow,
    const float* __restrict__ ob, const float* __restrict__ hin,
    const float* __restrict__ norm_w, const float* __restrict__ in_w,
    const float* __restrict__ in_b, float* __restrict__ hout,
    float* __restrict__ xin, float* __restrict__ zb, int has_out)
{
    const int t0 = blockIdx.x * TT;
    const int tid = threadIdx.x;
    const int lane = tid & 63;
    const int wv = tid >> 6;              // wave 0..3 -> tokens [wv*4, wv*4+4)
    __shared__ __align__(16) float ys[TT][ED];
    __shared__ __align__(16) float hn[TT][DM];

    float hval[4];
    const float nw = norm_w[lane];

    if (has_out) {
        {
            const float4* src = (const float4*)(y + (size_t)t0 * ED);
            float4* dst = (float4*)&ys[0][0];
            #pragma unroll
            for (int i = 0; i < (TT * ED / 4) / 256; ++i)
                dst[tid + i * 256] = src[tid + i * 256];
        }
        __syncthreads();
        float4 acc[4];
        #pragma unroll
        for (int j = 0; j < 4; ++j) acc[j] = make_float4(0.f, 0.f, 0.f, 0.f);
        #pragma unroll
        for (int p = 0; p < 2; ++p) {
            float4 w4[16];
            const float4* wr = (const float4*)(ow + lane * ED + p * 64);
            #pragma unroll
            for (int i = 0; i < 16; ++i) w4[i] = wr[i];
            #pragma unroll
            for (int j = 0; j < 4; ++j) {
                const float4* yv = (const float4*)&ys[wv * 4 + j][p * 64];
                #pragma unroll
                for (int i = 0; i < 16; ++i) {
                    float4 hv = yv[i];
                    acc[j].x = fmaf(hv.x, w4[i].x, acc[j].x);
                    acc[j].y = fmaf(hv.y, w4[i].y, acc[j].y);
                    acc[j].z = fmaf(hv.z, w4[i].z, acc[j].z);
                    acc[j].w = fmaf(hv.w, w4[i].w, acc[j].w);
                }
            }
        }
        const float obd = ob[lane];
        #pragma unroll
        for (int j = 0; j < 4; ++j) {
            const int tok = t0 + wv * 4 + j;
            hval[j] = hsum4(acc[j]) + obd + hin[(size_t)tok * DM + lane];
            hout[(size_t)tok * DM + lane] = hval[j];
        }
    } else {
        #pragma unroll
        for (int j = 0; j < 4; ++j)
            hval[j] = hin[(size_t)(t0 + wv * 4 + j) * DM + lane];
    }

    #pragma unroll
    for (int j = 0; j < 4; ++j) {
        float ss = hval[j] * hval[j];
        #pragma unroll
        for (int off = 32; off; off >>= 1) ss += __shfl_xor(ss, off, 64);
        const float sc = rsqrtf(ss * (1.0f / DM) + EPSV);
        hn[wv * 4 + j][lane] = hval[j] * sc * nw;
    }
    __syncthreads();

    {
        float4 w4[16];
        const float4* wr = (const float4*)(in_w + tid * DM);
        #pragma unroll
        for (int i = 0; i < 16; ++i) w4[i] = wr[i];
        const float bias = in_b[tid];
        #pragma unroll 4
        for (int tok = 0; tok < TT; ++tok) {
            const float4* hv4 = (const float4*)&hn[tok][0];
            float4 a4 = make_float4(0.f, 0.f, 0.f, 0.f);
            #pragma unroll
            for (int i = 0; i < 16; ++i) {
                float4 hv = hv4[i];
                a4.x = fmaf(hv.x, w4[i].x, a4.x);
                a4.y = fmaf(hv.y, w4[i].y, a4.y);
                a4.z = fmaf(hv.z, w4[i].z, a4.z);
                a4.w = fmaf(hv.w, w4[i].w, a4.w);
            }
            const float r = bias + hsum4(a4);
            if (tid < ED) xin[(size_t)(t0 + tok) * ED + tid] = r;
            else          zb[(size_t)(t0 + tok) * ED + (tid - ED)] = r;
        }
    }
}

// ---------------- K_B: causal dwconv + silu ; xproj ; dtproj+softplus — 16 tokens/block
__global__ __launch_bounds__(256) void k_conv_proj(
    const float* __restrict__ xin, const float* __restrict__ conv_w,
    const float* __restrict__ conv_b, const float* __restrict__ xproj_w,
    const float* __restrict__ dtproj_w, const float* __restrict__ dtproj_b,
    float* __restrict__ xc_out, float* __restrict__ delta_out,
    float* __restrict__ Bout, float* __restrict__ Cout)
{
    const int blk = blockIdx.x;             // BSZ * (Lseq/TT2) blocks
    const int b   = blk >> 7;               // Lseq/TT2 = 128
    const int ch  = blk & 127;
    const int l0  = ch * TT2;
    const size_t t0 = (size_t)b * Lseq + l0;
    const int tid = threadIdx.x;
    __shared__ __align__(16) float xs[(TT2 + DCONVK - 1) * ED];   // rows l0-15 .. l0+15
    __shared__ __align__(16) float xcs[TT2][ED];
    __shared__ float dts[TT2][DTRANK];

    {
        const int NV = (TT2 + DCONVK - 1) * ED / 4;   // 992
        for (int idx4 = tid; idx4 < NV; idx4 += 256) {
            const int row = idx4 >> 5;
            const int lrow = l0 - (DCONVK - 1) + row;
            float4 v = make_float4(0.f, 0.f, 0.f, 0.f);
            if (lrow >= 0)
                v = ((const float4*)(xin + ((size_t)b * Lseq + lrow) * ED))[idx4 & 31];
            ((float4*)xs)[idx4] = v;
        }
    }
    __syncthreads();

    const int e = tid & 127, half = tid >> 7;   // half: tokens [half*8, half*8+8)
    {
        float w[DCONVK];
        {
            const float4* cw = (const float4*)(conv_w + e * DCONVK);
            #pragma unroll
            for (int i = 0; i < 4; ++i) {
                float4 c = cw[i];
                w[i*4+0] = c.x; w[i*4+1] = c.y; w[i*4+2] = c.z; w[i*4+3] = c.w;
            }
        }
        const float cb = conv_b[e];
        #pragma unroll
        for (int j = 0; j < 8; ++j) {
            const int tok = half * 8 + j;
            float acc = cb;
            #pragma unroll
            for (int k = 0; k < DCONVK; ++k)
                acc = fmaf(xs[(tok + k) * ED + e], w[k], acc);
            const float xcv = acc * sigf(acc);
            xcs[tok][e] = xcv;
            xc_out[(t0 + tok) * ED + e] = xcv;
        }
    }
    __syncthreads();

    {
        const int wv = tid >> 6, lane = tid & 63;
        float4 acc[4];
        #pragma unroll
        for (int j = 0; j < 4; ++j) acc[j] = make_float4(0.f, 0.f, 0.f, 0.f);
        #pragma unroll
        for (int p = 0; p < 2; ++p) {
            float4 w4[16];
            const float4* wr = (const float4*)(xproj_w + lane * ED + p * 64);
            #pragma unroll
            for (int i = 0; i < 16; ++i) w4[i] = wr[i];
            #pragma unroll
            for (int j = 0; j < 4; ++j) {
                const float4* yv = (const float4*)&xcs[wv * 4 + j][p * 64];
                #pragma unroll
                for (int i = 0; i < 16; ++i) {
                    float4 hv = yv[i];
                    acc[j].x = fmaf(hv.x, w4[i].x, acc[j].x);
                    acc[j].y = fmaf(hv.y, w4[i].y, acc[j].y);
                    acc[j].z = fmaf(hv.z, w4[i].z, acc[j].z);
                    acc[j].w = fmaf(hv.w, w4[i].w, acc[j].w);
                }
            }
        }
        #pragma unroll
        for (int j = 0; j < 4; ++j) {
            const int tok = wv * 4 + j;
            const float v = hsum4(acc[j]);
            if (lane < DTRANK)            dts[tok][lane] = v;
            else if (lane < DTRANK + NST) Bout[(t0 + tok) * NST + (lane - DTRANK)] = v;
            else                          Cout[(t0 + tok) * NST + (lane - DTRANK - NST)] = v;
        }
        {
            const int ridx = lane & 3;
            const int ks   = (lane >> 2) & 3;
            const int tsub = lane >> 4;
            const int r4   = 64 + ridx;
            const int tok  = wv * 4 + tsub;
            const float4* wr = (const float4*)(xproj_w + r4 * ED + ks * 32);
            const float4* yv = (const float4*)&xcs[tok][ks * 32];
            float4 a4 = make_float4(0.f, 0.f, 0.f, 0.f);
            #pragma unroll
            for (int i = 0; i < 8; ++i) {
                float4 hv = yv[i]; float4 wv4 = wr[i];
                a4.x = fmaf(hv.x, wv4.x, a4.x);
                a4.y = fmaf(hv.y, wv4.y, a4.y);
                a4.z = fmaf(hv.z, wv4.z, a4.z);
                a4.w = fmaf(hv.w, wv4.w, a4.w);
            }
            float v = hsum4(a4);
            v += __shfl_xor(v, 4, 64);
            v += __shfl_xor(v, 8, 64);
            if (ks == 0) Cout[(t0 + tok) * NST + (r4 - DTRANK - NST)] = v;
        }
    }
    __syncthreads();

    {
        const float4 dwv = *(const float4*)(dtproj_w + e * DTRANK);
        const float bias = dtproj_b[e];
        #pragma unroll
        for (int j = 0; j < 8; ++j) {
            const int tok = half * 8 + j;
            float a = bias;
            a = fmaf(dts[tok][0], dwv.x, a);
            a = fmaf(dts[tok][1], dwv.y, a);
            a = fmaf(dts[tok][2], dwv.z, a);
            a = fmaf(dts[tok][3], dwv.w, a);
            const float sp = fmaxf(a, 0.f) + log1pf(__expf(-fabsf(a)));
            delta_out[(t0 + tok) * ED + e] = sp;
        }
    }
}

// ---------------- K3a: per-chunk local scan. 4 states/thread, 8 lanes/e, 32 e's/block.
// grid (NC, ED/32, BSZ), block 256.
__global__ __launch_bounds__(256) void k_scan_local(
    const float* __restrict__ delta, const float* __restrict__ Bv,
    const float* __restrict__ xc, const float* __restrict__ A_log,
    float* __restrict__ aprod, float* __restrict__ hloc)
{
    const int b = blockIdx.z;
    const int c = blockIdx.x;
    const int lane = threadIdx.x & 63;
    const int wv = threadIdx.x >> 6;
    const int e = blockIdx.y * 32 + wv * 8 + (lane >> 3);
    const int n0 = (lane & 7) * 4;

    const float4 al4 = *(const float4*)(A_log + e * NST + n0);
    float Aen[4] = { -__expf(al4.x), -__expf(al4.y), -__expf(al4.z), -__expf(al4.w) };
    float hs[4] = {0.f, 0.f, 0.f, 0.f};
    float ap[4] = {1.f, 1.f, 1.f, 1.f};

    const size_t base = (size_t)b * Lseq + (size_t)c * LC;
    #pragma unroll 2
    for (int l = 0; l < LC; ++l) {
        const size_t tok = base + l;
        const float de  = delta[tok * ED + e];
        const float xce = xc[tok * ED + e];
        const float4 B4 = *(const float4*)(Bv + tok * NST + n0);
        const float dexc = de * xce;
        float a;
        a = __expf(de * Aen[0]); hs[0] = fmaf(a, hs[0], B4.x * dexc); ap[0] *= a;
        a = __expf(de * Aen[1]); hs[1] = fmaf(a, hs[1], B4.y * dexc); ap[1] *= a;
        a = __expf(de * Aen[2]); hs[2] = fmaf(a, hs[2], B4.z * dexc); ap[2] *= a;
        a = __expf(de * Aen[3]); hs[3] = fmaf(a, hs[3], B4.w * dexc); ap[3] *= a;
    }
    const size_t idx = (((size_t)b * NC + c) * ED + e) * NST + n0;
    *(float4*)(aprod + idx) = make_float4(ap[0], ap[1], ap[2], ap[3]);
    *(float4*)(hloc + idx)  = make_float4(hs[0], hs[1], hs[2], hs[3]);
}

// ---------------- K3b (last layer only): chunk combine -> hend
__global__ __launch_bounds__(256) void k_scan_combine(
    const float* __restrict__ aprod, const float* __restrict__ hloc,
    float* __restrict__ hend)
{
    const int tid = blockIdx.x * 256 + threadIdx.x;   // 0..16383
    const int b = tid >> 12;                          // ED*NST = 4096
    const int en = tid & 4095;
    size_t idx = (size_t)b * NC * (ED * NST) + en;
    float h = 0.f;
    #pragma unroll 4
    for (int c = 0; c < NC; ++c) {
        h = fmaf(aprod[idx], h, hloc[idx]);
        idx += ED * NST;
    }
    hend[(size_t)b * (ED * NST) + en] = h;
}

// ---------------- K3c: per-chunk scan w/ inline prefix, emit y. Same tiling as K3a.
__global__ __launch_bounds__(256) void k_scan_y(
    const float* __restrict__ delta, const float* __restrict__ Bv,
    const float* __restrict__ Cv, const float* __restrict__ xc,
    const float* __restrict__ zb, const float* __restrict__ A_log,
    const float* __restrict__ Dp, const float* __restrict__ aprod,
    const float* __restrict__ hloc, float* __restrict__ y)
{
    const int b = blockIdx.z;
    const int c = blockIdx.x;
    const int lane = threadIdx.x & 63;
    const int wv = threadIdx.x >> 6;
    const int e = blockIdx.y * 32 + wv * 8 + (lane >> 3);
    const int nlane = lane & 7;
    const int n0 = nlane * 4;

    const float4 al4 = *(const float4*)(A_log + e * NST + n0);
    float Aen[4] = { -__expf(al4.x), -__expf(al4.y), -__expf(al4.z), -__expf(al4.w) };
    const float dpe = Dp[e];

    // prefix over chunks < c (float4 coalesced)
    float hs[4] = {0.f, 0.f, 0.f, 0.f};
    {
        size_t idx = ((size_t)b * NC * ED + e) * NST + n0;
        for (int cc = 0; cc < c; ++cc) {
            const float4 a4 = *(const float4*)(aprod + idx);
            const float4 h4 = *(const float4*)(hloc + idx);
            hs[0] = fmaf(a4.x, hs[0], h4.x);
            hs[1] = fmaf(a4.y, hs[1], h4.y);
            hs[2] = fmaf(a4.z, hs[2], h4.z);
            hs[3] = fmaf(a4.w, hs[3], h4.w);
            idx += (size_t)ED * NST;
        }
    }

    const size_t base = (size_t)b * Lseq + (size_t)c * LC;
    for (int l = 0; l < LC; ++l) {
        const size_t tok = base + l;
        const float de  = delta[tok * ED + e];
        const float xce = xc[tok * ED + e];
        const float4 B4 = *(const float4*)(Bv + tok * NST + n0);
        const float4 C4 = *(const float4*)(Cv + tok * NST + n0);
        const float dexc = de * xce;
        float a;
        a = __expf(de * Aen[0]); hs[0] = fmaf(a, hs[0], B4.x * dexc);
        a = __expf(de * Aen[1]); hs[1] = fmaf(a, hs[1], B4.y * dexc);
        a = __expf(de * Aen[2]); hs[2] = fmaf(a, hs[2], B4.z * dexc);
        a = __expf(de * Aen[3]); hs[3] = fmaf(a, hs[3], B4.w * dexc);
        float p = hs[0] * C4.x;
        p = fmaf(hs[1], C4.y, p);
        p = fmaf(hs[2], C4.z, p);
        p = fmaf(hs[3], C4.w, p);
        p += __shfl_xor(p, 1, 64);
        p += __shfl_xor(p, 2, 64);
        p += __shfl_xor(p, 4, 64);
        if (nlane == 0) {
            const float zi = zb[tok * ED + e];
            y[tok * ED + e] = (p + dpe * xce) * (zi * sigf(zi));
        }
    }
}

// ---------------- K5: last layer head: y(L-1) from hend, then fc dot -> logits
__global__ __launch_bounds__(128) void k_final_last(
    const float* __restrict__ hend, const float* __restrict__ Cv,
    const float* __restrict__ xc, const float* __restrict__ zb,
    const float* __restrict__ Dp, const float* __restrict__ fcw,
    const float* __restrict__ fcb, float* __restrict__ out)
{
    const int b = blockIdx.x;
    const int e = threadIdx.x;       // 0..127
    const size_t tok = (size_t)b * Lseq + (Lseq - 1);
    const float* hp = hend + (size_t)b * (ED * NST) + e * NST;
    const float* cp = Cv + tok * NST;
    float p = 0.f;
    #pragma unroll
    for (int n = 0; n < NST; ++n) p = fmaf(hp[n], cp[n], p);
    const float xce = xc[tok * ED + e];
    const float zi  = zb[tok * ED + e];
    float val = (p + Dp[e] * xce) * (zi * sigf(zi)) * fcw[e];
    __shared__ float sred[2];
    #pragma unroll
    for (int off = 32; off; off >>= 1) val += __shfl_xor(val, off, 64);
    if ((threadIdx.x & 63) == 0) sred[threadIdx.x >> 6] = val;
    __syncthreads();
    if (threadIdx.x == 0) out[b] = sred[0] + sred[1] + fcb[0];
}

extern "C" void kernel_launch(void* const* d_in, const int* in_sizes, int n_in,
                              void* d_out, int out_size, void* d_ws, size_t ws_size,
                              hipStream_t stream)
{
    const float* x         = (const float*)d_in[0];
    const float* in_w      = (const float*)d_in[1];
    const float* in_b      = (const float*)d_in[2];
    const float* conv_w    = (const float*)d_in[3];
    const float* conv_b    = (const float*)d_in[4];
    const float* xproj_w   = (const float*)d_in[5];
    const float* dtproj_w  = (const float*)d_in[6];
    const float* dtproj_b  = (const float*)d_in[7];
    const float* A_log     = (const float*)d_in[8];
    const float* Dp        = (const float*)d_in[9];
    const float* outproj_w = (const float*)d_in[10];
    const float* outproj_b = (const float*)d_in[11];
    const float* norm_w    = (const float*)d_in[12];
    const float* fc_w      = (const float*)d_in[13];
    const float* fc_b      = (const float*)d_in[14];

    const size_t TOK = (size_t)BSZ * Lseq;
    float* ws = (float*)d_ws;
    float* h0    = ws; ws += TOK * DM;
    float* h1    = ws; ws += TOK * DM;
    float* xin   = ws; ws += TOK * ED;   // reused as y after the scan
    float* zbuf  = ws; ws += TOK * ED;
    float* xc    = ws; ws += TOK * ED;
    float* dlt   = ws; ws += TOK * ED;
    float* Bv    = ws; ws += TOK * NST;
    float* Cv    = ws; ws += TOK * NST;
    float* aprod = ws; ws += (size_t)BSZ * NC * ED * NST;
    float* hloc  = ws; ws += (size_t)BSZ * NC * ED * NST;
    float* hend  = ws; ws += (size_t)BSZ * ED * NST;

    const float* hres = x;               // residual stream input for current layer
    float* hbufs[2] = { h0, h1 };

    for (int i = 0; i < NLAYERS; ++i) {
        const int last = (i == NLAYERS - 1);
        if (i == 0) {
            k_layer_gemm<<<(int)(TOK / TT), 256, 0, stream>>>(
                nullptr, nullptr, nullptr, x, norm_w, in_w, in_b,
                nullptr, xin, zbuf, 0);
        } else {
            float* hout = hbufs[i & 1];
            k_layer_gemm<<<(int)(TOK / TT), 256, 0, stream>>>(
                xin /* y of prev layer */,
                outproj_w + (size_t)(i - 1) * DM * ED,
                outproj_b + (size_t)(i - 1) * DM,
                hres, norm_w + (size_t)i * DM,
                in_w + (size_t)i * 2 * ED * DM, in_b + (size_t)i * 2 * ED,
                hout, xin, zbuf, 1);
            hres = hout;
        }
        k_conv_proj<<<(int)(TOK / TT2), 256, 0, stream>>>(
            xin, conv_w + (size_t)i * ED * DCONVK, conv_b + (size_t)i * ED,
            xproj_w + (size_t)i * (DTRANK + 2 * NST) * ED,
            dtproj_w + (size_t)i * ED * DTRANK, dtproj_b + (size_t)i * ED,
            xc, dlt, Bv, Cv);
        const float* Alog_i = A_log + (size_t)i * ED * NST;
        k_scan_local<<<dim3(NC, ED / 32, BSZ), 256, 0, stream>>>(
            dlt, Bv, xc, Alog_i, aprod, hloc);
        if (!last) {
            k_scan_y<<<dim3(NC, ED / 32, BSZ), 256, 0, stream>>>(
                dlt, Bv, Cv, xc, zbuf, Alog_i, Dp + (size_t)i * ED,
                aprod, hloc, xin);
        } else {
            k_scan_combine<<<(BSZ * ED * NST) / 256, 256, 0, stream>>>(
                aprod, hloc, hend);
            k_final_last<<<BSZ, 128, 0, stream>>>(
                hend, Cv, xc, zbuf, Dp + (size_t)i * ED, fc_w, fc_b, (float*)d_out);
        }
    }
}

// Round 7
// 451.210 us; speedup vs baseline: 15.3634x; 1.0711x over previous
//
#include <hip/hip_runtime.h>
#include <math.h>

#define BSZ 4
#define Lseq 2048
#define DM 64
#define ED 128
#define NST 32
#define DCONVK 16
#define NLAYERS 4
#define DTRANK 4
#define EPSV 1e-5f
#define NC 64                 // chunks along L for the scan
#define LC (Lseq / NC)        // 32 steps per chunk
#define TT 16                 // tokens per block in k_layer_gemm
#define TT2 16                // tokens per block in k_conv_proj

__device__ __forceinline__ float sigf(float x) { return 1.0f / (1.0f + __expf(-x)); }
__device__ __forceinline__ float hsum4(float4 a) { return (a.x + a.y) + (a.z + a.w); }

// ---------------- K_A: [outproj(prev y) + residual] + rmsnorm + inproj, 16 tokens/block
__global__ __launch_bounds__(256) void k_layer_gemm(
    const float* __restrict__ y, const float* __restrict__ ow,
    const float* __restrict__ ob, const float* __restrict__ hin,
    const float* __restrict__ norm_w, const float* __restrict__ in_w,
    const float* __restrict__ in_b, float* __restrict__ hout,
    float* __restrict__ xin, float* __restrict__ zb, int has_out)
{
    const int t0 = blockIdx.x * TT;
    const int tid = threadIdx.x;
    const int lane = tid & 63;
    const int wv = tid >> 6;              // wave 0..3 -> tokens [wv*4, wv*4+4)
    __shared__ __align__(16) float ys[TT][ED];
    __shared__ __align__(16) float hn[TT][DM];

    float hval[4];
    const float nw = norm_w[lane];

    if (has_out) {
        {
            const float4* src = (const float4*)(y + (size_t)t0 * ED);
            float4* dst = (float4*)&ys[0][0];
            #pragma unroll
            for (int i = 0; i < (TT * ED / 4) / 256; ++i)
                dst[tid + i * 256] = src[tid + i * 256];
        }
        __syncthreads();
        float4 acc[4];
        #pragma unroll
        for (int j = 0; j < 4; ++j) acc[j] = make_float4(0.f, 0.f, 0.f, 0.f);
        #pragma unroll
        for (int p = 0; p < 2; ++p) {
            float4 w4[16];
            const float4* wr = (const float4*)(ow + lane * ED + p * 64);
            #pragma unroll
            for (int i = 0; i < 16; ++i) w4[i] = wr[i];
            #pragma unroll
            for (int j = 0; j < 4; ++j) {
                const float4* yv = (const float4*)&ys[wv * 4 + j][p * 64];
                #pragma unroll
                for (int i = 0; i < 16; ++i) {
                    float4 hv = yv[i];
                    acc[j].x = fmaf(hv.x, w4[i].x, acc[j].x);
                    acc[j].y = fmaf(hv.y, w4[i].y, acc[j].y);
                    acc[j].z = fmaf(hv.z, w4[i].z, acc[j].z);
                    acc[j].w = fmaf(hv.w, w4[i].w, acc[j].w);
                }
            }
        }
        const float obd = ob[lane];
        #pragma unroll
        for (int j = 0; j < 4; ++j) {
            const int tok = t0 + wv * 4 + j;
            hval[j] = hsum4(acc[j]) + obd + hin[(size_t)tok * DM + lane];
            hout[(size_t)tok * DM + lane] = hval[j];
        }
    } else {
        #pragma unroll
        for (int j = 0; j < 4; ++j)
            hval[j] = hin[(size_t)(t0 + wv * 4 + j) * DM + lane];
    }

    #pragma unroll
    for (int j = 0; j < 4; ++j) {
        float ss = hval[j] * hval[j];
        #pragma unroll
        for (int off = 32; off; off >>= 1) ss += __shfl_xor(ss, off, 64);
        const float sc = rsqrtf(ss * (1.0f / DM) + EPSV);
        hn[wv * 4 + j][lane] = hval[j] * sc * nw;
    }
    __syncthreads();

    {
        float4 w4[16];
        const float4* wr = (const float4*)(in_w + tid * DM);
        #pragma unroll
        for (int i = 0; i < 16; ++i) w4[i] = wr[i];
        const float bias = in_b[tid];
        #pragma unroll 4
        for (int tok = 0; tok < TT; ++tok) {
            const float4* hv4 = (const float4*)&hn[tok][0];
            float4 a4 = make_float4(0.f, 0.f, 0.f, 0.f);
            #pragma unroll
            for (int i = 0; i < 16; ++i) {
                float4 hv = hv4[i];
                a4.x = fmaf(hv.x, w4[i].x, a4.x);
                a4.y = fmaf(hv.y, w4[i].y, a4.y);
                a4.z = fmaf(hv.z, w4[i].z, a4.z);
                a4.w = fmaf(hv.w, w4[i].w, a4.w);
            }
            const float r = bias + hsum4(a4);
            if (tid < ED) xin[(size_t)(t0 + tok) * ED + tid] = r;
            else          zb[(size_t)(t0 + tok) * ED + (tid - ED)] = r;
        }
    }
}

// ---------------- K_B: causal dwconv + silu ; xproj ; dtproj+softplus — 16 tokens/block
__global__ __launch_bounds__(256) void k_conv_proj(
    const float* __restrict__ xin, const float* __restrict__ conv_w,
    const float* __restrict__ conv_b, const float* __restrict__ xproj_w,
    const float* __restrict__ dtproj_w, const float* __restrict__ dtproj_b,
    float* __restrict__ xc_out, float* __restrict__ delta_out,
    float* __restrict__ Bout, float* __restrict__ Cout)
{
    const int blk = blockIdx.x;             // BSZ * (Lseq/TT2) blocks
    const int b   = blk >> 7;               // Lseq/TT2 = 128
    const int ch  = blk & 127;
    const int l0  = ch * TT2;
    const size_t t0 = (size_t)b * Lseq + l0;
    const int tid = threadIdx.x;
    __shared__ __align__(16) float xs[(TT2 + DCONVK - 1) * ED];   // rows l0-15 .. l0+15
    __shared__ __align__(16) float xcs[TT2][ED];
    __shared__ float dts[TT2][DTRANK];

    {
        const int NV = (TT2 + DCONVK - 1) * ED / 4;   // 992
        for (int idx4 = tid; idx4 < NV; idx4 += 256) {
            const int row = idx4 >> 5;
            const int lrow = l0 - (DCONVK - 1) + row;
            float4 v = make_float4(0.f, 0.f, 0.f, 0.f);
            if (lrow >= 0)
                v = ((const float4*)(xin + ((size_t)b * Lseq + lrow) * ED))[idx4 & 31];
            ((float4*)xs)[idx4] = v;
        }
    }
    __syncthreads();

    const int e = tid & 127, half = tid >> 7;   // half: tokens [half*8, half*8+8)
    {
        float w[DCONVK];
        {
            const float4* cw = (const float4*)(conv_w + e * DCONVK);
            #pragma unroll
            for (int i = 0; i < 4; ++i) {
                float4 c = cw[i];
                w[i*4+0] = c.x; w[i*4+1] = c.y; w[i*4+2] = c.z; w[i*4+3] = c.w;
            }
        }
        const float cb = conv_b[e];
        #pragma unroll
        for (int j = 0; j < 8; ++j) {
            const int tok = half * 8 + j;
            float acc = cb;
            #pragma unroll
            for (int k = 0; k < DCONVK; ++k)
                acc = fmaf(xs[(tok + k) * ED + e], w[k], acc);
            const float xcv = acc * sigf(acc);
            xcs[tok][e] = xcv;
            xc_out[(t0 + tok) * ED + e] = xcv;
        }
    }
    __syncthreads();

    {
        const int wv = tid >> 6, lane = tid & 63;
        float4 acc[4];
        #pragma unroll
        for (int j = 0; j < 4; ++j) acc[j] = make_float4(0.f, 0.f, 0.f, 0.f);
        #pragma unroll
        for (int p = 0; p < 2; ++p) {
            float4 w4[16];
            const float4* wr = (const float4*)(xproj_w + lane * ED + p * 64);
            #pragma unroll
            for (int i = 0; i < 16; ++i) w4[i] = wr[i];
            #pragma unroll
            for (int j = 0; j < 4; ++j) {
                const float4* yv = (const float4*)&xcs[wv * 4 + j][p * 64];
                #pragma unroll
                for (int i = 0; i < 16; ++i) {
                    float4 hv = yv[i];
                    acc[j].x = fmaf(hv.x, w4[i].x, acc[j].x);
                    acc[j].y = fmaf(hv.y, w4[i].y, acc[j].y);
                    acc[j].z = fmaf(hv.z, w4[i].z, acc[j].z);
                    acc[j].w = fmaf(hv.w, w4[i].w, acc[j].w);
                }
            }
        }
        #pragma unroll
        for (int j = 0; j < 4; ++j) {
            const int tok = wv * 4 + j;
            const float v = hsum4(acc[j]);
            if (lane < DTRANK)            dts[tok][lane] = v;
            else if (lane < DTRANK + NST) Bout[(t0 + tok) * NST + (lane - DTRANK)] = v;
            else                          Cout[(t0 + tok) * NST + (lane - DTRANK - NST)] = v;
        }
        {
            const int ridx = lane & 3;
            const int ks   = (lane >> 2) & 3;
            const int tsub = lane >> 4;
            const int r4   = 64 + ridx;
            const int tok  = wv * 4 + tsub;
            const float4* wr = (const float4*)(xproj_w + r4 * ED + ks * 32);
            const float4* yv = (const float4*)&xcs[tok][ks * 32];
            float4 a4 = make_float4(0.f, 0.f, 0.f, 0.f);
            #pragma unroll
            for (int i = 0; i < 8; ++i) {
                float4 hv = yv[i]; float4 wv4 = wr[i];
                a4.x = fmaf(hv.x, wv4.x, a4.x);
                a4.y = fmaf(hv.y, wv4.y, a4.y);
                a4.z = fmaf(hv.z, wv4.z, a4.z);
                a4.w = fmaf(hv.w, wv4.w, a4.w);
            }
            float v = hsum4(a4);
            v += __shfl_xor(v, 4, 64);
            v += __shfl_xor(v, 8, 64);
            if (ks == 0) Cout[(t0 + tok) * NST + (r4 - DTRANK - NST)] = v;
        }
    }
    __syncthreads();

    {
        const float4 dwv = *(const float4*)(dtproj_w + e * DTRANK);
        const float bias = dtproj_b[e];
        #pragma unroll
        for (int j = 0; j < 8; ++j) {
            const int tok = half * 8 + j;
            float a = bias;
            a = fmaf(dts[tok][0], dwv.x, a);
            a = fmaf(dts[tok][1], dwv.y, a);
            a = fmaf(dts[tok][2], dwv.z, a);
            a = fmaf(dts[tok][3], dwv.w, a);
            const float sp = fmaxf(a, 0.f) + log1pf(__expf(-fabsf(a)));
            delta_out[(t0 + tok) * ED + e] = sp;
        }
    }
}

// ---------------- K3a: per-chunk local scan. 4 states/thread, 8 lanes/e, 32 e's/block.
// grid (NC, ED/32, BSZ), block 256.
__global__ __launch_bounds__(256) void k_scan_local(
    const float* __restrict__ delta, const float* __restrict__ Bv,
    const float* __restrict__ xc, const float* __restrict__ A_log,
    float* __restrict__ aprod, float* __restrict__ hloc)
{
    const int b = blockIdx.z;
    const int c = blockIdx.x;
    const int lane = threadIdx.x & 63;
    const int wv = threadIdx.x >> 6;
    const int e = blockIdx.y * 32 + wv * 8 + (lane >> 3);
    const int n0 = (lane & 7) * 4;

    const float4 al4 = *(const float4*)(A_log + e * NST + n0);
    float Aen[4] = { -__expf(al4.x), -__expf(al4.y), -__expf(al4.z), -__expf(al4.w) };
    float hs[4] = {0.f, 0.f, 0.f, 0.f};
    float ap[4] = {1.f, 1.f, 1.f, 1.f};

    const size_t base = (size_t)b * Lseq + (size_t)c * LC;
    #pragma unroll 4
    for (int l = 0; l < LC; ++l) {
        const size_t tok = base + l;
        const float de  = delta[tok * ED + e];
        const float xce = xc[tok * ED + e];
        const float4 B4 = *(const float4*)(Bv + tok * NST + n0);
        const float dexc = de * xce;
        float a;
        a = __expf(de * Aen[0]); hs[0] = fmaf(a, hs[0], B4.x * dexc); ap[0] *= a;
        a = __expf(de * Aen[1]); hs[1] = fmaf(a, hs[1], B4.y * dexc); ap[1] *= a;
        a = __expf(de * Aen[2]); hs[2] = fmaf(a, hs[2], B4.z * dexc); ap[2] *= a;
        a = __expf(de * Aen[3]); hs[3] = fmaf(a, hs[3], B4.w * dexc); ap[3] *= a;
    }
    const size_t idx = (((size_t)b * NC + c) * ED + e) * NST + n0;
    *(float4*)(aprod + idx) = make_float4(ap[0], ap[1], ap[2], ap[3]);
    *(float4*)(hloc + idx)  = make_float4(hs[0], hs[1], hs[2], hs[3]);
}

// ---------------- K3b (every layer): chunk combine. Rewrites hloc in place into the
// per-chunk INITIAL states; also emits final state hend (used by last layer).
__global__ __launch_bounds__(256) void k_scan_combine(
    const float* __restrict__ aprod, float* __restrict__ hloc,
    float* __restrict__ hend)
{
    const int tid = blockIdx.x * 256 + threadIdx.x;   // 0..16383
    const int b = tid >> 12;                          // ED*NST = 4096
    const int en = tid & 4095;
    size_t idx = (size_t)b * NC * (ED * NST) + en;
    float h = 0.f;
    #pragma unroll 4
    for (int c = 0; c < NC; ++c) {
        const float a = aprod[idx];
        const float u = hloc[idx];
        hloc[idx] = h;                 // initial state for chunk c
        h = fmaf(a, h, u);
        idx += ED * NST;
    }
    hend[(size_t)b * (ED * NST) + en] = h;
}

// ---------------- K3c: per-chunk scan from hinit (uniform work), emit y.
__global__ __launch_bounds__(256) void k_scan_y(
    const float* __restrict__ delta, const float* __restrict__ Bv,
    const float* __restrict__ Cv, const float* __restrict__ xc,
    const float* __restrict__ zb, const float* __restrict__ A_log,
    const float* __restrict__ Dp, const float* __restrict__ hinit,
    float* __restrict__ y)
{
    const int b = blockIdx.z;
    const int c = blockIdx.x;
    const int lane = threadIdx.x & 63;
    const int wv = threadIdx.x >> 6;
    const int e = blockIdx.y * 32 + wv * 8 + (lane >> 3);
    const int nlane = lane & 7;
    const int n0 = nlane * 4;

    const float4 al4 = *(const float4*)(A_log + e * NST + n0);
    float Aen[4] = { -__expf(al4.x), -__expf(al4.y), -__expf(al4.z), -__expf(al4.w) };
    const float dpe = Dp[e];

    float hs[4];
    {
        const float4 h4 = *(const float4*)(hinit + (((size_t)b * NC + c) * ED + e) * NST + n0);
        hs[0] = h4.x; hs[1] = h4.y; hs[2] = h4.z; hs[3] = h4.w;
    }

    const size_t base = (size_t)b * Lseq + (size_t)c * LC;
    #pragma unroll 2
    for (int l = 0; l < LC; ++l) {
        const size_t tok = base + l;
        const float de  = delta[tok * ED + e];
        const float xce = xc[tok * ED + e];
        const float4 B4 = *(const float4*)(Bv + tok * NST + n0);
        const float4 C4 = *(const float4*)(Cv + tok * NST + n0);
        const float dexc = de * xce;
        float a;
        a = __expf(de * Aen[0]); hs[0] = fmaf(a, hs[0], B4.x * dexc);
        a = __expf(de * Aen[1]); hs[1] = fmaf(a, hs[1], B4.y * dexc);
        a = __expf(de * Aen[2]); hs[2] = fmaf(a, hs[2], B4.z * dexc);
        a = __expf(de * Aen[3]); hs[3] = fmaf(a, hs[3], B4.w * dexc);
        float p = hs[0] * C4.x;
        p = fmaf(hs[1], C4.y, p);
        p = fmaf(hs[2], C4.z, p);
        p = fmaf(hs[3], C4.w, p);
        p += __shfl_xor(p, 1, 64);
        p += __shfl_xor(p, 2, 64);
        p += __shfl_xor(p, 4, 64);
        if (nlane == 0) {
            const float zi = zb[tok * ED + e];
            y[tok * ED + e] = (p + dpe * xce) * (zi * sigf(zi));
        }
    }
}

// ---------------- K5: last layer head: y(L-1) from hend, then fc dot -> logits
__global__ __launch_bounds__(128) void k_final_last(
    const float* __restrict__ hend, const float* __restrict__ Cv,
    const float* __restrict__ xc, const float* __restrict__ zb,
    const float* __restrict__ Dp, const float* __restrict__ fcw,
    const float* __restrict__ fcb, float* __restrict__ out)
{
    const int b = blockIdx.x;
    const int e = threadIdx.x;       // 0..127
    const size_t tok = (size_t)b * Lseq + (Lseq - 1);
    const float* hp = hend + (size_t)b * (ED * NST) + e * NST;
    const float* cp = Cv + tok * NST;
    float p = 0.f;
    #pragma unroll
    for (int n = 0; n < NST; ++n) p = fmaf(hp[n], cp[n], p);
    const float xce = xc[tok * ED + e];
    const float zi  = zb[tok * ED + e];
    float val = (p + Dp[e] * xce) * (zi * sigf(zi)) * fcw[e];
    __shared__ float sred[2];
    #pragma unroll
    for (int off = 32; off; off >>= 1) val += __shfl_xor(val, off, 64);
    if ((threadIdx.x & 63) == 0) sred[threadIdx.x >> 6] = val;
    __syncthreads();
    if (threadIdx.x == 0) out[b] = sred[0] + sred[1] + fcb[0];
}

extern "C" void kernel_launch(void* const* d_in, const int* in_sizes, int n_in,
                              void* d_out, int out_size, void* d_ws, size_t ws_size,
                              hipStream_t stream)
{
    const float* x         = (const float*)d_in[0];
    const float* in_w      = (const float*)d_in[1];
    const float* in_b      = (const float*)d_in[2];
    const float* conv_w    = (const float*)d_in[3];
    const float* conv_b    = (const float*)d_in[4];
    const float* xproj_w   = (const float*)d_in[5];
    const float* dtproj_w  = (const float*)d_in[6];
    const float* dtproj_b  = (const float*)d_in[7];
    const float* A_log     = (const float*)d_in[8];
    const float* Dp        = (const float*)d_in[9];
    const float* outproj_w = (const float*)d_in[10];
    const float* outproj_b = (const float*)d_in[11];
    const float* norm_w    = (const float*)d_in[12];
    const float* fc_w      = (const float*)d_in[13];
    const float* fc_b      = (const float*)d_in[14];

    const size_t TOK = (size_t)BSZ * Lseq;
    float* ws = (float*)d_ws;
    float* h0    = ws; ws += TOK * DM;
    float* h1    = ws; ws += TOK * DM;
    float* xin   = ws; ws += TOK * ED;   // reused as y after the scan
    float* zbuf  = ws; ws += TOK * ED;
    float* xc    = ws; ws += TOK * ED;
    float* dlt   = ws; ws += TOK * ED;
    float* Bv    = ws; ws += TOK * NST;
    float* Cv    = ws; ws += TOK * NST;
    float* aprod = ws; ws += (size_t)BSZ * NC * ED * NST;
    float* hloc  = ws; ws += (size_t)BSZ * NC * ED * NST;   // becomes hinit in-place
    float* hend  = ws; ws += (size_t)BSZ * ED * NST;

    const float* hres = x;               // residual stream input for current layer
    float* hbufs[2] = { h0, h1 };

    for (int i = 0; i < NLAYERS; ++i) {
        const int last = (i == NLAYERS - 1);
        if (i == 0) {
            k_layer_gemm<<<(int)(TOK / TT), 256, 0, stream>>>(
                nullptr, nullptr, nullptr, x, norm_w, in_w, in_b,
                nullptr, xin, zbuf, 0);
        } else {
            float* hout = hbufs[i & 1];
            k_layer_gemm<<<(int)(TOK / TT), 256, 0, stream>>>(
                xin /* y of prev layer */,
                outproj_w + (size_t)(i - 1) * DM * ED,
                outproj_b + (size_t)(i - 1) * DM,
                hres, norm_w + (size_t)i * DM,
                in_w + (size_t)i * 2 * ED * DM, in_b + (size_t)i * 2 * ED,
                hout, xin, zbuf, 1);
            hres = hout;
        }
        k_conv_proj<<<(int)(TOK / TT2), 256, 0, stream>>>(
            xin, conv_w + (size_t)i * ED * DCONVK, conv_b + (size_t)i * ED,
            xproj_w + (size_t)i * (DTRANK + 2 * NST) * ED,
            dtproj_w + (size_t)i * ED * DTRANK, dtproj_b + (size_t)i * ED,
            xc, dlt, Bv, Cv);
        const float* Alog_i = A_log + (size_t)i * ED * NST;
        k_scan_local<<<dim3(NC, ED / 32, BSZ), 256, 0, stream>>>(
            dlt, Bv, xc, Alog_i, aprod, hloc);
        k_scan_combine<<<(BSZ * ED * NST) / 256, 256, 0, stream>>>(
            aprod, hloc, hend);
        if (!last) {
            k_scan_y<<<dim3(NC, ED / 32, BSZ), 256, 0, stream>>>(
                dlt, Bv, Cv, xc, zbuf, Alog_i, Dp + (size_t)i * ED,
                hloc, xin);
        } else {
            k_final_last<<<BSZ, 128, 0, stream>>>(
                hend, Cv, xc, zbuf, Dp + (size_t)i * ED, fc_w, fc_b, (float*)d_out);
        }
    }
}